// Round 12
// baseline (1391.366 us; speedup 1.0000x reference)
//
#include <hip/hip_runtime.h>
#include <math.h>

#define NTHREADS 256
#define IN_C 128
#define HID 64
#define OUT_C 40
#define N_LAYERS 8
#define ALPHA 0.1f
#define BN_EPS 1e-5f
#define BKT_SHIFT 9   // 512-node buckets for the two-pass CSR fill

typedef float f32x4 __attribute__((ext_vector_type(4)));
typedef _Float16 f16;
typedef _Float16 f16x4 __attribute__((ext_vector_type(4)));
typedef _Float16 f16x8 __attribute__((ext_vector_type(8)));

__device__ __forceinline__ f32x4 ld4(const float* p) { return *(const f32x4*)p; }

__device__ __forceinline__ f32x4 ldh4(const f16* p) {
  f16x4 v = *(const f16x4*)p;
  return __builtin_convertvector(v, f32x4);
}

__device__ __forceinline__ f32x4 bnrelu(f32x4 v, f32x4 k1, f32x4 k2) {
  f32x4 r = v * k1 + k2;
  r.x = fmaxf(r.x, 0.f); r.y = fmaxf(r.y, 0.f);
  r.z = fmaxf(r.z, 0.f); r.w = fmaxf(r.w, 0.f);
  return r;
}

// sum over the 4 16-lane groups (lanes l, l+16, l+32, l+48)
__device__ __forceinline__ f32x4 xreduce(f32x4 v) {
  v.x += __shfl_xor(v.x, 16); v.y += __shfl_xor(v.y, 16);
  v.z += __shfl_xor(v.z, 16); v.w += __shfl_xor(v.w, 16);
  v.x += __shfl_xor(v.x, 32); v.y += __shfl_xor(v.y, 32);
  v.z += __shfl_xor(v.z, 32); v.w += __shfl_xor(v.w, 32);
  return v;
}

__device__ __forceinline__ float bcast(float v, int lane) {
  return __int_as_float(__builtin_amdgcn_readlane(__float_as_int(v), lane));
}

// ---------------- setup kernels ----------------

// sums layout: per-layer slot l at [l*1024], channel c at offset c*16
__global__ void k_zero(int* __restrict__ cnt, float* __restrict__ sumP,
                       float* __restrict__ sumsqP, f16* __restrict__ svpad,
                       int n) {
  int i = blockIdx.x * NTHREADS + threadIdx.x;
  if (i < n) cnt[i] = 0;
  if (i < N_LAYERS * 1024) { sumP[i] = 0.f; sumsqP[i] = 0.f; }
  if (i < 256) {  // zero the 16 pad rows of sv (MFMA A-frag tail)
    f16x4 z = {(f16)0.f, (f16)0.f, (f16)0.f, (f16)0.f};
    ((f16x4*)svpad)[i] = z;
  }
}

__global__ void k_hist(const int* __restrict__ col, int* __restrict__ cnt, int E) {
  int e = blockIdx.x * NTHREADS + threadIdx.x;
  if (e < E) atomicAdd(&cnt[col[e]], 1);
}

// scan pass 1 + dinv (deg = cnt + self loop)
__global__ void k_scan1(const int* __restrict__ cnt, int* __restrict__ offs,
                        int* __restrict__ partials, float* __restrict__ dinv,
                        int n) {
  __shared__ int sh[NTHREADS];
  int t = threadIdx.x, i = blockIdx.x * NTHREADS + t;
  int v = (i < n) ? cnt[i] : 0;
  if (i < n) dinv[i] = rsqrtf((float)v + 1.0f);
  sh[t] = v;
  __syncthreads();
  int run = v;
  for (int d = 1; d < NTHREADS; d <<= 1) {
    int add = (t >= d) ? sh[t - d] : 0;
    __syncthreads();
    run += add;
    sh[t] = run;
    __syncthreads();
  }
  if (i < n) offs[i] = run - v;
  if (t == NTHREADS - 1) partials[blockIdx.x] = run;
}

__global__ void k_scan2(int* __restrict__ partials, int nb) {
  __shared__ int sh[512];
  int t = threadIdx.x;
  int v = (t < nb) ? partials[t] : 0;
  sh[t] = v;
  __syncthreads();
  int run = v;
  for (int d = 1; d < 512; d <<= 1) {
    int add = (t >= d) ? sh[t - d] : 0;
    __syncthreads();
    run += add;
    sh[t] = run;
    __syncthreads();
  }
  if (t < nb) partials[t] = run - v;
}

// pass 3: final offs/cur; also seed bucket cursors bcur[b] = offs[b*512]
__global__ void k_scan3(int* __restrict__ offs, int* __restrict__ cur,
                        const int* __restrict__ partials,
                        int* __restrict__ bcur, int n, int E) {
  int i = blockIdx.x * NTHREADS + threadIdx.x;
  if (i < n) {
    int v = offs[i] + partials[i >> 8];
    offs[i] = v;
    cur[i] = v;
    if ((i & ((1 << BKT_SHIFT) - 1)) == 0) bcur[i >> BKT_SHIFT] = v;
  }
  if (i == 0) offs[n] = E;
}

// ---- bucketed CSR fill, pass A: scatter (col,row) into 32KB bucket regions.
// LDS histogram per 4096-edge block -> one global atomic per (block,bucket)
// -> dense sequential writes inside each bucket region (full-sector dirty).
__global__ __launch_bounds__(NTHREADS) void k_bucketA(
    const int* __restrict__ row, const int* __restrict__ col,
    int* __restrict__ bcur, long long* __restrict__ tmp, int E, int nb) {
  __shared__ int lhist[512];
  __shared__ int lbase[512];
  int t = threadIdx.x;
  for (int i = t; i < nb; i += NTHREADS) lhist[i] = 0;
  __syncthreads();
  int start = blockIdx.x * 4096;
  int end = min(E, start + 4096);
  for (int e = start + t; e < end; e += NTHREADS)
    atomicAdd(&lhist[col[e] >> BKT_SHIFT], 1);
  __syncthreads();
  for (int i = t; i < nb; i += NTHREADS) {
    int c = lhist[i];
    lbase[i] = c ? atomicAdd(&bcur[i], c) : 0;
    lhist[i] = 0;
  }
  __syncthreads();
  for (int e = start + t; e < end; e += NTHREADS) {
    int cl = col[e];
    int b = cl >> BKT_SHIFT;
    int slot = atomicAdd(&lhist[b], 1);
    tmp[lbase[b] + slot] = ((long long)cl << 32) | (unsigned int)row[e];
  }
}

// ---- pass B: one block per bucket; stream the region, place records at
// final CSR positions (all inside the same ~32KB window -> L2-local RMW,
// lines fully dirtied; cur atomics hit a 2KB window).
__global__ __launch_bounds__(NTHREADS) void k_bucketB(
    const long long* __restrict__ tmp, const int* __restrict__ offs,
    int* __restrict__ cur, int* __restrict__ ew, int n) {
  int b = blockIdx.x;
  int lo = b << BKT_SHIFT;
  int hi = min(n, lo + (1 << BKT_SHIFT));
  int s = offs[lo], e2 = offs[hi];
  for (int j = s + threadIdx.x; j < e2; j += NTHREADS) {
    long long r = tmp[j];
    int cl = (int)(r >> 32);
    int rw = (int)(r & 0xffffffffLL);
    int pos = atomicAdd(&cur[cl], 1);
    ew[pos] = rw;
  }
}

// ---------------- h0 = relu(x@W0+b0) (fp16) and hp = dinv*h0 ----------------
__global__ __launch_bounds__(NTHREADS) void k_gemm0(
    const float* __restrict__ x, const float* __restrict__ W0,
    const float* __restrict__ b0, const float* __restrict__ dinv,
    f16* __restrict__ h016, f16* __restrict__ hp, int n) {
  int t = threadIdx.x;
  int lane = t & 63;
  int c = lane;
  float Wc[IN_C];
#pragma unroll
  for (int k = 0; k < IN_C; k++) Wc[k] = W0[k * HID + c];
  float bias = b0[c];
  int half = lane >> 5, li = lane & 31;
  int wg = blockIdx.x * (NTHREADS / 64) + (t >> 6);
  int NW = gridDim.x * (NTHREADS / 64);
  int npairs = (n + 1) >> 1;
  for (int p = wg; p < npairs; p += NW) {
    int r = 2 * p + half;
    f32x4 xv = {0.f, 0.f, 0.f, 0.f};
    if (r < n) xv = ld4(x + (size_t)r * IN_C + li * 4);
    float acc0 = bias, acc1 = bias;
#pragma unroll
    for (int k = 0; k < IN_C; k++) {
      int sl = k >> 2;
      float comp = xv[k & 3];
      float a0 = bcast(comp, sl);
      float a1 = bcast(comp, 32 + sl);
      acc0 += a0 * Wc[k];
      acc1 += a1 * Wc[k];
    }
    acc0 = fmaxf(acc0, 0.f);
    acc1 = fmaxf(acc1, 0.f);
    int r0 = 2 * p, r1 = 2 * p + 1;
    if (r0 < n) {
      float d0 = dinv[r0];
      h016[(size_t)r0 * HID + c] = (f16)acc0;
      hp[(size_t)r0 * HID + c] = (f16)(d0 * acc0);
    }
    if (r1 < n) {
      float d1 = dinv[r1];
      h016[(size_t)r1 * HID + c] = (f16)acc1;
      hp[(size_t)r1 * HID + c] = (f16)(d1 * acc1);
    }
  }
}

// ---------------- gather-only kernel (r10 structure, barrier-free) ----------
// sv[i] = (1-a)*di*(acc + hp[i]) + a*h0[i],   acc = sum_j hp[src_j]
// One 16-lane group per row; 8-deep chunks; no LDS/barriers/launch_bounds
// (r4/5/7: any tight VGPR cap spills loop state to scratch).
__global__ void k_gather(
    const f16* __restrict__ hp, const f16* __restrict__ h0,
    const float* __restrict__ dinv, const int* __restrict__ offs,
    const int* __restrict__ ew, f16* __restrict__ sv, int n) {
  int t = threadIdx.x;
  int lane = t & 63;
  int eg = lane >> 4, li = lane & 15, c4 = li << 2;
  int i = blockIdx.x * 16 + (t >> 6) * 4 + eg;  // this group's row
  if (i >= n) return;
  int jb = offs[i], je = offs[i + 1];
  float di = dinv[i];
  f16x4 hs16 = *(const f16x4*)(hp + (size_t)i * HID + c4);
  f16x4 h016v = *(const f16x4*)(h0 + (size_t)i * HID + c4);
  f32x4 acc = {0.f, 0.f, 0.f, 0.f};
  int j = jb;
  for (; j + 8 <= je; j += 8) {
    int q0 = ew[j + 0];
    int q1 = ew[j + 1];
    int q2 = ew[j + 2];
    int q3 = ew[j + 3];
    int q4 = ew[j + 4];
    int q5 = ew[j + 5];
    int q6 = ew[j + 6];
    int q7 = ew[j + 7];
    f16x4 u0 = *(const f16x4*)(hp + (size_t)q0 * HID + c4);
    f16x4 u1 = *(const f16x4*)(hp + (size_t)q1 * HID + c4);
    f16x4 u2 = *(const f16x4*)(hp + (size_t)q2 * HID + c4);
    f16x4 u3 = *(const f16x4*)(hp + (size_t)q3 * HID + c4);
    f16x4 u4 = *(const f16x4*)(hp + (size_t)q4 * HID + c4);
    f16x4 u5 = *(const f16x4*)(hp + (size_t)q5 * HID + c4);
    f16x4 u6 = *(const f16x4*)(hp + (size_t)q6 * HID + c4);
    f16x4 u7 = *(const f16x4*)(hp + (size_t)q7 * HID + c4);
    acc += __builtin_convertvector(u0, f32x4);
    acc += __builtin_convertvector(u1, f32x4);
    acc += __builtin_convertvector(u2, f32x4);
    acc += __builtin_convertvector(u3, f32x4);
    acc += __builtin_convertvector(u4, f32x4);
    acc += __builtin_convertvector(u5, f32x4);
    acc += __builtin_convertvector(u6, f32x4);
    acc += __builtin_convertvector(u7, f32x4);
  }
  for (; j < je; j++) {
    acc += ldh4(hp + (size_t)ew[j] * HID + c4);
  }
  f32x4 hs = __builtin_convertvector(hs16, f32x4);
  f32x4 h0v = __builtin_convertvector(h016v, f32x4);
  f32x4 sval = (1.f - ALPHA) * (di * (acc + hs)) + ALPHA * h0v;
  *(f16x4*)(sv + (size_t)i * HID + c4) = __builtin_convertvector(sval, f16x4);
}

// ---------------- MFMA conv + BN stats (r10 structure) ----------------------
// S2 = SV @ W',  W' = (1-beta)I + beta*W (built during LDS staging, fp16).
__global__ __launch_bounds__(NTHREADS) void k_conv(
    const f16* __restrict__ sv, const float* __restrict__ Wl,
    f16* __restrict__ sout, float* __restrict__ sumL,
    float* __restrict__ sumsqL, float beta, int n) {
  __shared__ __align__(16) float Wsh[HID * HID];  // W' staged, 16 KB
  __shared__ f32x4 red4[2][4][16];
  int t = threadIdx.x;
  // stage W' = beta*W + (1-beta)*I
  for (int m = t; m < HID * HID / 4; m += NTHREADS) {
    f32x4 wv = ((const f32x4*)Wl)[m];
    wv *= beta;
    int base = m * 4;
    int k = base >> 6, c0 = base & 63;
    if (k >= c0 && k < c0 + 4) wv[k - c0] += (1.f - beta);
    ((f32x4*)Wsh)[m] = wv;
  }
  __syncthreads();
  int lane = t & 63, wid = t >> 6;
  int lm = lane & 15, lk = lane >> 4;
  // B fragments: 4 col-tiles x 2 K-steps, cast to fp16
  f16x8 bf[4][2];
#pragma unroll
  for (int nt = 0; nt < 4; nt++) {
#pragma unroll
    for (int ks = 0; ks < 2; ks++) {
      int c = nt * 16 + lm;
#pragma unroll
      for (int i = 0; i < 8; i++) {
        int k = ks * 32 + lk * 8 + i;
        bf[nt][ks][i] = (f16)Wsh[k * HID + c];
      }
    }
  }
  float ssum[4] = {0.f, 0.f, 0.f, 0.f}, ssq[4] = {0.f, 0.f, 0.f, 0.f};
  int nblk = (n + 15) >> 4;
  for (int blk = blockIdx.x * 4 + wid; blk < nblk; blk += gridDim.x * 4) {
    int r0 = blk * 16;
    const f16* ap = sv + (size_t)(r0 + lm) * HID + lk * 8;  // pad rows zeroed
    f16x8 a0 = *(const f16x8*)(ap);
    f16x8 a1 = *(const f16x8*)(ap + 32);
#pragma unroll
    for (int nt = 0; nt < 4; nt++) {
      f32x4 z = {0.f, 0.f, 0.f, 0.f};
      z = __builtin_amdgcn_mfma_f32_16x16x32_f16(a0, bf[nt][0], z, 0, 0, 0);
      z = __builtin_amdgcn_mfma_f32_16x16x32_f16(a1, bf[nt][1], z, 0, 0, 0);
#pragma unroll
      for (int reg = 0; reg < 4; reg++) {
        int r = r0 + lk * 4 + reg;
        if (r < n) {
          float v = z[reg];
          sout[(size_t)r * HID + nt * 16 + lm] = (f16)v;
          ssum[nt] += v;
          ssq[nt] += v * v;
        }
      }
    }
  }
  // stats reduce: lanes l, l+16, l+32, l+48 share the same channel set
  f32x4 sumv = {ssum[0], ssum[1], ssum[2], ssum[3]};
  f32x4 sqv = {ssq[0], ssq[1], ssq[2], ssq[3]};
  sumv = xreduce(sumv);
  sqv = xreduce(sqv);
  if (lk == 0) { red4[0][wid][lm] = sumv; red4[1][wid][lm] = sqv; }
  __syncthreads();
  if (t < 16) {
    f32x4 a = red4[0][0][t] + red4[0][1][t] + red4[0][2][t] + red4[0][3][t];
    f32x4 b = red4[1][0][t] + red4[1][1][t] + red4[1][2][t] + red4[1][3][t];
    atomicAdd(&sumL[(0 * 16 + t) * 16], a.x);
    atomicAdd(&sumL[(1 * 16 + t) * 16], a.y);
    atomicAdd(&sumL[(2 * 16 + t) * 16], a.z);
    atomicAdd(&sumL[(3 * 16 + t) * 16], a.w);
    atomicAdd(&sumsqL[(0 * 16 + t) * 16], b.x);
    atomicAdd(&sumsqL[(1 * 16 + t) * 16], b.y);
    atomicAdd(&sumsqL[(2 * 16 + t) * 16], b.z);
    atomicAdd(&sumsqL[(3 * 16 + t) * 16], b.w);
  }
}

// per-block inline BN-affine from the sums slot
__device__ __forceinline__ void stats_to_lds(
    const float* __restrict__ sumL, const float* __restrict__ sumsqL,
    const float* __restrict__ gamma_l, const float* __restrict__ beta_l,
    float* ms, int t, int n) {
  if (t < 64) {
    float s = sumL[t * 16], sq = sumsqL[t * 16];
    float mu = s / (float)n;
    float var = sq / (float)n - mu * mu;
    float iv = rsqrtf(var + BN_EPS);
    float k1 = iv * gamma_l[t];
    ms[t] = k1;
    ms[64 + t] = beta_l[t] - mu * k1;
  }
  __syncthreads();
}

// hp = dinv * relu(BN(s)): the pre-scaled gather operand for the next layer
__global__ __launch_bounds__(NTHREADS) void k_bnrelu(
    const f16* __restrict__ s, const float* __restrict__ sumL,
    const float* __restrict__ sumsqL, const float* __restrict__ gamma_l,
    const float* __restrict__ beta_l, const float* __restrict__ dinv,
    f16* __restrict__ hp, int n) {
  __shared__ __align__(16) float ms[128];
  int t = threadIdx.x;
  stats_to_lds(sumL, sumsqL, gamma_l, beta_l, ms, t, n);
  int idx = blockIdx.x * NTHREADS + t;  // x4 index
  if (idx < n * (HID / 4)) {
    int c4 = idx & 15;
    int row = idx >> 4;
    f32x4 v = ldh4(s + (size_t)idx * 4);
    f32x4 k1 = *(const f32x4*)(ms + c4 * 4);
    f32x4 k2 = *(const f32x4*)(ms + 64 + c4 * 4);
    v = bnrelu(v, k1, k2);
    float di = dinv[row];
    v = di * v;
    ((f16x4*)hp)[idx] = __builtin_convertvector(v, f16x4);
  }
}

// out = relu(BN_7(s)) @ W_out + b_out   (affine computed inline from slot 7)
__global__ __launch_bounds__(NTHREADS) void k_out(
    const f16* __restrict__ s, const float* __restrict__ sumL,
    const float* __restrict__ sumsqL, const float* __restrict__ gamma_l,
    const float* __restrict__ beta_l, const float* __restrict__ Wout,
    const float* __restrict__ bout, float* __restrict__ out, int n) {
  __shared__ float Ws[HID * OUT_C];
  __shared__ float bs[OUT_C];
  __shared__ __align__(16) float ms[128];
  int t = threadIdx.x;
  for (int m = t; m < HID * OUT_C; m += NTHREADS) Ws[m] = Wout[m];
  if (t < OUT_C) bs[t] = bout[t];
  stats_to_lds(sumL, sumsqL, gamma_l, beta_l, ms, t, n);
  int idx = blockIdx.x * NTHREADS + t;
  if (idx < n * OUT_C) {
    int row = idx / OUT_C;
    int c = idx - row * OUT_C;
    float acc = bs[c];
    const f16* sr = s + (size_t)row * HID;
    for (int kk = 0; kk < HID / 4; kk++) {
      f32x4 a = ldh4(sr + kk * 4);
      f32x4 k1 = *(const f32x4*)(ms + kk * 4);
      f32x4 k2 = *(const f32x4*)(ms + 64 + kk * 4);
      a = bnrelu(a, k1, k2);
      int k = kk * 4;
      acc += a.x * Ws[(k + 0) * OUT_C + c] + a.y * Ws[(k + 1) * OUT_C + c] +
             a.z * Ws[(k + 2) * OUT_C + c] + a.w * Ws[(k + 3) * OUT_C + c];
    }
    out[idx] = acc;
  }
}

// ---------------- host ----------------

extern "C" void kernel_launch(void* const* d_in, const int* in_sizes, int n_in,
                              void* d_out, int out_size, void* d_ws, size_t ws_size,
                              hipStream_t stream) {
  const float* x = (const float*)d_in[0];
  const int* ei = (const int*)d_in[1];
  const float* W0 = (const float*)d_in[2];
  const float* b0 = (const float*)d_in[3];
  const float* convW = (const float*)d_in[4];
  const float* bn_gamma = (const float*)d_in[5];
  const float* bn_beta = (const float*)d_in[6];
  const float* W_out = (const float*)d_in[7];
  const float* b_out = (const float*)d_in[8];
  float* out = (float*)d_out;

  int n = in_sizes[0] / IN_C;   // 100000
  int E = in_sizes[1] / 2;      // 1600000
  const int* row = ei;
  const int* col = ei + E;
  int NB = (n + (1 << BKT_SHIFT) - 1) >> BKT_SHIFT;  // 196 buckets

  char* w = (char*)d_ws;
  auto alloc = [&](size_t bytes) {
    char* p = w;
    w += (bytes + 255) & ~(size_t)255;
    return p;
  };
  float* dinv    = (float*)alloc((size_t)n * 4);
  int*   cnt     = (int*)alloc((size_t)n * 4);
  int*   offs    = (int*)alloc((size_t)(n + 1) * 4);
  int*   cur     = (int*)alloc((size_t)n * 4);
  int*   partials= (int*)alloc(512 * 4);
  int*   bcur    = (int*)alloc(512 * 4);
  int*   ew      = (int*)alloc((size_t)E * 4);          // 4B records
  long long* tmp = (long long*)alloc((size_t)E * 8);    // bucketed (col,row)
  f16*   h016    = (f16*)alloc((size_t)n * HID * 2);
  f16*   hp      = (f16*)alloc((size_t)n * HID * 2);    // dinv * relu(BN(s))
  f16*   sv      = (f16*)alloc((size_t)(n + 16) * HID * 2);  // +16 pad rows
  f16*   sb      = (f16*)alloc((size_t)n * HID * 2);    // conv output s_l
  float* sumP    = (float*)alloc((size_t)N_LAYERS * 1024 * 4);
  float* sumsqP  = (float*)alloc((size_t)N_LAYERS * 1024 * 4);

  int gN = (n + NTHREADS - 1) / NTHREADS;   // 391
  int gE = (E + NTHREADS - 1) / NTHREADS;   // 6250
  int gA = (E + 4095) / 4096;               // 391 (pass A blocks)
  int gRow = (n + 15) / 16;                 // 6250
  int gConv = (gRow + 3) / 4;               // 1563
  int gV = (n * (HID / 4) + NTHREADS - 1) / NTHREADS;

  k_zero<<<gN, NTHREADS, 0, stream>>>(cnt, sumP, sumsqP,
                                      sv + (size_t)n * HID, n);
  k_hist<<<gE, NTHREADS, 0, stream>>>(col, cnt, E);
  k_scan1<<<gN, NTHREADS, 0, stream>>>(cnt, offs, partials, dinv, n);
  k_scan2<<<1, 512, 0, stream>>>(partials, gN);
  k_scan3<<<gN, NTHREADS, 0, stream>>>(offs, cur, partials, bcur, n, E);
  k_bucketA<<<gA, NTHREADS, 0, stream>>>(row, col, bcur, tmp, E, NB);
  k_bucketB<<<NB, NTHREADS, 0, stream>>>(tmp, offs, cur, ew, n);

  k_gemm0<<<1024, NTHREADS, 0, stream>>>(x, W0, b0, dinv, h016, hp, n);

  for (int l = 0; l < N_LAYERS; l++) {
    float beta = logf(0.5f / (float)(l + 1) + 1.0f);
    if (l > 0) {  // hp = dinv * relu(BN_{l-1}(s_{l-1})) using slot l-1
      k_bnrelu<<<gV, NTHREADS, 0, stream>>>(
          sb, sumP + (size_t)(l - 1) * 1024, sumsqP + (size_t)(l - 1) * 1024,
          bn_gamma + (l - 1) * HID, bn_beta + (l - 1) * HID, dinv, hp, n);
    }
    k_gather<<<gRow, NTHREADS, 0, stream>>>(hp, h016, dinv, offs, ew, sv, n);
    k_conv<<<gConv, NTHREADS, 0, stream>>>(sv, convW + (size_t)l * HID * HID,
                                           sb, sumP + (size_t)l * 1024,
                                           sumsqP + (size_t)l * 1024, beta, n);
  }

  // s_7 in sb; k_out applies BN_7 (slot 7) + relu inline, then output GEMM
  k_out<<<((size_t)n * OUT_C + NTHREADS - 1) / NTHREADS, NTHREADS, 0, stream>>>(
      sb, sumP + (size_t)7 * 1024, sumsqP + (size_t)7 * 1024,
      bn_gamma + 7 * HID, bn_beta + 7 * HID, W_out, b_out, out, n);
}

// Round 13
// 1329.553 us; speedup vs baseline: 1.0465x; 1.0465x over previous
//
#include <hip/hip_runtime.h>
#include <math.h>

#define NTHREADS 256
#define IN_C 128
#define HID 64
#define OUT_C 40
#define N_LAYERS 8
#define ALPHA 0.1f
#define BN_EPS 1e-5f
#define BKT_SHIFT 9   // 512-node buckets for the two-pass CSR fill

typedef float f32x4 __attribute__((ext_vector_type(4)));
typedef _Float16 f16;
typedef _Float16 f16x4 __attribute__((ext_vector_type(4)));
typedef _Float16 f16x8 __attribute__((ext_vector_type(8)));

__device__ __forceinline__ f32x4 ld4(const float* p) { return *(const f32x4*)p; }

__device__ __forceinline__ f32x4 ldh4(const f16* p) {
  f16x4 v = *(const f16x4*)p;
  return __builtin_convertvector(v, f32x4);
}

__device__ __forceinline__ f32x4 bnrelu(f32x4 v, f32x4 k1, f32x4 k2) {
  f32x4 r = v * k1 + k2;
  r.x = fmaxf(r.x, 0.f); r.y = fmaxf(r.y, 0.f);
  r.z = fmaxf(r.z, 0.f); r.w = fmaxf(r.w, 0.f);
  return r;
}

// sum over the 4 16-lane groups (lanes l, l+16, l+32, l+48)
__device__ __forceinline__ f32x4 xreduce(f32x4 v) {
  v.x += __shfl_xor(v.x, 16); v.y += __shfl_xor(v.y, 16);
  v.z += __shfl_xor(v.z, 16); v.w += __shfl_xor(v.w, 16);
  v.x += __shfl_xor(v.x, 32); v.y += __shfl_xor(v.y, 32);
  v.z += __shfl_xor(v.z, 32); v.w += __shfl_xor(v.w, 32);
  return v;
}

// ---------------- setup kernels ----------------

// sums layout: per-layer slot l at [l*1024], channel c at offset c*16
__global__ void k_zero(int* __restrict__ cnt, float* __restrict__ sumP,
                       float* __restrict__ sumsqP, f16* __restrict__ svpad,
                       int n) {
  int i = blockIdx.x * NTHREADS + threadIdx.x;
  if (i < n) cnt[i] = 0;
  if (i < N_LAYERS * 1024) { sumP[i] = 0.f; sumsqP[i] = 0.f; }
  if (i < 256) {  // zero the 16 pad rows of sv (MFMA A-frag tail)
    f16x4 z = {(f16)0.f, (f16)0.f, (f16)0.f, (f16)0.f};
    ((f16x4*)svpad)[i] = z;
  }
}

__global__ void k_hist(const int* __restrict__ col, int* __restrict__ cnt, int E) {
  int e = blockIdx.x * NTHREADS + threadIdx.x;
  if (e < E) atomicAdd(&cnt[col[e]], 1);
}

// scan pass 1 + dinv (deg = cnt + self loop)
__global__ void k_scan1(const int* __restrict__ cnt, int* __restrict__ offs,
                        int* __restrict__ partials, float* __restrict__ dinv,
                        int n) {
  __shared__ int sh[NTHREADS];
  int t = threadIdx.x, i = blockIdx.x * NTHREADS + t;
  int v = (i < n) ? cnt[i] : 0;
  if (i < n) dinv[i] = rsqrtf((float)v + 1.0f);
  sh[t] = v;
  __syncthreads();
  int run = v;
  for (int d = 1; d < NTHREADS; d <<= 1) {
    int add = (t >= d) ? sh[t - d] : 0;
    __syncthreads();
    run += add;
    sh[t] = run;
    __syncthreads();
  }
  if (i < n) offs[i] = run - v;
  if (t == NTHREADS - 1) partials[blockIdx.x] = run;
}

__global__ void k_scan2(int* __restrict__ partials, int nb) {
  __shared__ int sh[512];
  int t = threadIdx.x;
  int v = (t < nb) ? partials[t] : 0;
  sh[t] = v;
  __syncthreads();
  int run = v;
  for (int d = 1; d < 512; d <<= 1) {
    int add = (t >= d) ? sh[t - d] : 0;
    __syncthreads();
    run += add;
    sh[t] = run;
    __syncthreads();
  }
  if (t < nb) partials[t] = run - v;
}

// pass 3: final offs/cur; also seed bucket cursors bcur[b] = offs[b*512]
__global__ void k_scan3(int* __restrict__ offs, int* __restrict__ cur,
                        const int* __restrict__ partials,
                        int* __restrict__ bcur, int n, int E) {
  int i = blockIdx.x * NTHREADS + threadIdx.x;
  if (i < n) {
    int v = offs[i] + partials[i >> 8];
    offs[i] = v;
    cur[i] = v;
    if ((i & ((1 << BKT_SHIFT) - 1)) == 0) bcur[i >> BKT_SHIFT] = v;
  }
  if (i == 0) offs[n] = E;
}

// ---- bucketed CSR fill, pass A: scatter (col,row) into 32KB bucket regions.
__global__ __launch_bounds__(NTHREADS) void k_bucketA(
    const int* __restrict__ row, const int* __restrict__ col,
    int* __restrict__ bcur, long long* __restrict__ tmp, int E, int nb) {
  __shared__ int lhist[512];
  __shared__ int lbase[512];
  int t = threadIdx.x;
  for (int i = t; i < nb; i += NTHREADS) lhist[i] = 0;
  __syncthreads();
  int start = blockIdx.x * 4096;
  int end = min(E, start + 4096);
  for (int e = start + t; e < end; e += NTHREADS)
    atomicAdd(&lhist[col[e] >> BKT_SHIFT], 1);
  __syncthreads();
  for (int i = t; i < nb; i += NTHREADS) {
    int c = lhist[i];
    lbase[i] = c ? atomicAdd(&bcur[i], c) : 0;
    lhist[i] = 0;
  }
  __syncthreads();
  for (int e = start + t; e < end; e += NTHREADS) {
    int cl = col[e];
    int b = cl >> BKT_SHIFT;
    int slot = atomicAdd(&lhist[b], 1);
    tmp[lbase[b] + slot] = ((long long)cl << 32) | (unsigned int)row[e];
  }
}

// ---- pass B: one block per bucket; stream the region, place records at
// final CSR positions (all inside the same ~32KB window).
__global__ __launch_bounds__(NTHREADS) void k_bucketB(
    const long long* __restrict__ tmp, const int* __restrict__ offs,
    int* __restrict__ cur, int* __restrict__ ew, int n) {
  int b = blockIdx.x;
  int lo = b << BKT_SHIFT;
  int hi = min(n, lo + (1 << BKT_SHIFT));
  int s = offs[lo], e2 = offs[hi];
  for (int j = s + threadIdx.x; j < e2; j += NTHREADS) {
    long long r = tmp[j];
    int cl = (int)(r >> 32);
    int rw = (int)(r & 0xffffffffLL);
    int pos = atomicAdd(&cur[cl], 1);
    ew[pos] = rw;
  }
}

// ---------------- MFMA gemm0: h0 = relu(x@W0+b0), hp = dinv*h0 ----------------
// Per wave: one 16-row tile. B-frags = full W0 (128x64) as fp16
// bf[4 col-tiles][4 K-steps]; A-frags converted from fp32 x on the fly.
// Same operand layout as k_conv (verified r10): A lane-> row lm, k=ks*32+lk*8+i;
// C/D col = nt*16+lm, row = r0+lk*4+reg.
__global__ void k_gemm0(
    const float* __restrict__ x, const float* __restrict__ W0,
    const float* __restrict__ b0, const float* __restrict__ dinv,
    f16* __restrict__ h016, f16* __restrict__ hp, int n) {
  int t = threadIdx.x;
  int lane = t & 63, wid = t >> 6;
  int lm = lane & 15, lk = lane >> 4;
  f16x8 bf[4][4];
  float bv[4];
#pragma unroll
  for (int nt = 0; nt < 4; nt++) {
    int c = nt * 16 + lm;
    bv[nt] = b0[c];
#pragma unroll
    for (int ks = 0; ks < 4; ks++) {
#pragma unroll
      for (int i = 0; i < 8; i++) {
        bf[nt][ks][i] = (f16)W0[(ks * 32 + lk * 8 + i) * HID + c];
      }
    }
  }
  int nblk = (n + 15) >> 4;
  for (int blk = blockIdx.x * 4 + wid; blk < nblk; blk += gridDim.x * 4) {
    int r0 = blk * 16;
    int rA = min(r0 + lm, n - 1);
    const float* xr = x + (size_t)rA * IN_C + lk * 8;
    f16x8 af[4];
#pragma unroll
    for (int ks = 0; ks < 4; ks++) {
      f32x4 lo = ld4(xr + ks * 32);
      f32x4 hi = ld4(xr + ks * 32 + 4);
      f16x4 l16 = __builtin_convertvector(lo, f16x4);
      f16x4 h16 = __builtin_convertvector(hi, f16x4);
#pragma unroll
      for (int i = 0; i < 4; i++) { af[ks][i] = l16[i]; af[ks][4 + i] = h16[i]; }
    }
    float dv[4];
#pragma unroll
    for (int reg = 0; reg < 4; reg++)
      dv[reg] = dinv[min(r0 + lk * 4 + reg, n - 1)];
#pragma unroll
    for (int nt = 0; nt < 4; nt++) {
      f32x4 z = {0.f, 0.f, 0.f, 0.f};
      z = __builtin_amdgcn_mfma_f32_16x16x32_f16(af[0], bf[nt][0], z, 0, 0, 0);
      z = __builtin_amdgcn_mfma_f32_16x16x32_f16(af[1], bf[nt][1], z, 0, 0, 0);
      z = __builtin_amdgcn_mfma_f32_16x16x32_f16(af[2], bf[nt][2], z, 0, 0, 0);
      z = __builtin_amdgcn_mfma_f32_16x16x32_f16(af[3], bf[nt][3], z, 0, 0, 0);
#pragma unroll
      for (int reg = 0; reg < 4; reg++) {
        int r = r0 + lk * 4 + reg;
        if (r < n) {
          float v = fmaxf(z[reg] + bv[nt], 0.f);
          h016[(size_t)r * HID + nt * 16 + lm] = (f16)v;
          hp[(size_t)r * HID + nt * 16 + lm] = (f16)(dv[reg] * v);
        }
      }
    }
  }
}

// ---------------- gather-only kernel (r10 structure, barrier-free) ----------
// sv[i] = (1-a)*di*(acc + hp[i]) + a*h0[i],   acc = sum_j hp[src_j]
// One 16-lane group per row; 8-deep chunks; no LDS/barriers/launch_bounds
// (r4/5/7: any tight VGPR cap spills loop state to scratch).
__global__ void k_gather(
    const f16* __restrict__ hp, const f16* __restrict__ h0,
    const float* __restrict__ dinv, const int* __restrict__ offs,
    const int* __restrict__ ew, f16* __restrict__ sv, int n) {
  int t = threadIdx.x;
  int lane = t & 63;
  int eg = lane >> 4, li = lane & 15, c4 = li << 2;
  int i = blockIdx.x * 16 + (t >> 6) * 4 + eg;  // this group's row
  if (i >= n) return;
  int jb = offs[i], je = offs[i + 1];
  float di = dinv[i];
  f16x4 hs16 = *(const f16x4*)(hp + (size_t)i * HID + c4);
  f16x4 h016v = *(const f16x4*)(h0 + (size_t)i * HID + c4);
  f32x4 acc = {0.f, 0.f, 0.f, 0.f};
  int j = jb;
  for (; j + 8 <= je; j += 8) {
    int q0 = ew[j + 0];
    int q1 = ew[j + 1];
    int q2 = ew[j + 2];
    int q3 = ew[j + 3];
    int q4 = ew[j + 4];
    int q5 = ew[j + 5];
    int q6 = ew[j + 6];
    int q7 = ew[j + 7];
    f16x4 u0 = *(const f16x4*)(hp + (size_t)q0 * HID + c4);
    f16x4 u1 = *(const f16x4*)(hp + (size_t)q1 * HID + c4);
    f16x4 u2 = *(const f16x4*)(hp + (size_t)q2 * HID + c4);
    f16x4 u3 = *(const f16x4*)(hp + (size_t)q3 * HID + c4);
    f16x4 u4 = *(const f16x4*)(hp + (size_t)q4 * HID + c4);
    f16x4 u5 = *(const f16x4*)(hp + (size_t)q5 * HID + c4);
    f16x4 u6 = *(const f16x4*)(hp + (size_t)q6 * HID + c4);
    f16x4 u7 = *(const f16x4*)(hp + (size_t)q7 * HID + c4);
    acc += __builtin_convertvector(u0, f32x4);
    acc += __builtin_convertvector(u1, f32x4);
    acc += __builtin_convertvector(u2, f32x4);
    acc += __builtin_convertvector(u3, f32x4);
    acc += __builtin_convertvector(u4, f32x4);
    acc += __builtin_convertvector(u5, f32x4);
    acc += __builtin_convertvector(u6, f32x4);
    acc += __builtin_convertvector(u7, f32x4);
  }
  for (; j < je; j++) {
    acc += ldh4(hp + (size_t)ew[j] * HID + c4);
  }
  f32x4 hs = __builtin_convertvector(hs16, f32x4);
  f32x4 h0v = __builtin_convertvector(h016v, f32x4);
  f32x4 sval = (1.f - ALPHA) * (di * (acc + hs)) + ALPHA * h0v;
  *(f16x4*)(sv + (size_t)i * HID + c4) = __builtin_convertvector(sval, f16x4);
}

// ---------------- MFMA conv + BN stats (r10 structure) ----------------------
// S2 = SV @ W',  W' = (1-beta)I + beta*W (built during LDS staging, fp16).
__global__ __launch_bounds__(NTHREADS) void k_conv(
    const f16* __restrict__ sv, const float* __restrict__ Wl,
    f16* __restrict__ sout, float* __restrict__ sumL,
    float* __restrict__ sumsqL, float beta, int n) {
  __shared__ __align__(16) float Wsh[HID * HID];  // W' staged, 16 KB
  __shared__ f32x4 red4[2][4][16];
  int t = threadIdx.x;
  // stage W' = beta*W + (1-beta)*I
  for (int m = t; m < HID * HID / 4; m += NTHREADS) {
    f32x4 wv = ((const f32x4*)Wl)[m];
    wv *= beta;
    int base = m * 4;
    int k = base >> 6, c0 = base & 63;
    if (k >= c0 && k < c0 + 4) wv[k - c0] += (1.f - beta);
    ((f32x4*)Wsh)[m] = wv;
  }
  __syncthreads();
  int lane = t & 63, wid = t >> 6;
  int lm = lane & 15, lk = lane >> 4;
  // B fragments: 4 col-tiles x 2 K-steps, cast to fp16
  f16x8 bf[4][2];
#pragma unroll
  for (int nt = 0; nt < 4; nt++) {
#pragma unroll
    for (int ks = 0; ks < 2; ks++) {
      int c = nt * 16 + lm;
#pragma unroll
      for (int i = 0; i < 8; i++) {
        int k = ks * 32 + lk * 8 + i;
        bf[nt][ks][i] = (f16)Wsh[k * HID + c];
      }
    }
  }
  float ssum[4] = {0.f, 0.f, 0.f, 0.f}, ssq[4] = {0.f, 0.f, 0.f, 0.f};
  int nblk = (n + 15) >> 4;
  for (int blk = blockIdx.x * 4 + wid; blk < nblk; blk += gridDim.x * 4) {
    int r0 = blk * 16;
    const f16* ap = sv + (size_t)(r0 + lm) * HID + lk * 8;  // pad rows zeroed
    f16x8 a0 = *(const f16x8*)(ap);
    f16x8 a1 = *(const f16x8*)(ap + 32);
#pragma unroll
    for (int nt = 0; nt < 4; nt++) {
      f32x4 z = {0.f, 0.f, 0.f, 0.f};
      z = __builtin_amdgcn_mfma_f32_16x16x32_f16(a0, bf[nt][0], z, 0, 0, 0);
      z = __builtin_amdgcn_mfma_f32_16x16x32_f16(a1, bf[nt][1], z, 0, 0, 0);
#pragma unroll
      for (int reg = 0; reg < 4; reg++) {
        int r = r0 + lk * 4 + reg;
        if (r < n) {
          float v = z[reg];
          sout[(size_t)r * HID + nt * 16 + lm] = (f16)v;
          ssum[nt] += v;
          ssq[nt] += v * v;
        }
      }
    }
  }
  // stats reduce: lanes l, l+16, l+32, l+48 share the same channel set
  f32x4 sumv = {ssum[0], ssum[1], ssum[2], ssum[3]};
  f32x4 sqv = {ssq[0], ssq[1], ssq[2], ssq[3]};
  sumv = xreduce(sumv);
  sqv = xreduce(sqv);
  if (lk == 0) { red4[0][wid][lm] = sumv; red4[1][wid][lm] = sqv; }
  __syncthreads();
  if (t < 16) {
    f32x4 a = red4[0][0][t] + red4[0][1][t] + red4[0][2][t] + red4[0][3][t];
    f32x4 b = red4[1][0][t] + red4[1][1][t] + red4[1][2][t] + red4[1][3][t];
    atomicAdd(&sumL[(0 * 16 + t) * 16], a.x);
    atomicAdd(&sumL[(1 * 16 + t) * 16], a.y);
    atomicAdd(&sumL[(2 * 16 + t) * 16], a.z);
    atomicAdd(&sumL[(3 * 16 + t) * 16], a.w);
    atomicAdd(&sumsqL[(0 * 16 + t) * 16], b.x);
    atomicAdd(&sumsqL[(1 * 16 + t) * 16], b.y);
    atomicAdd(&sumsqL[(2 * 16 + t) * 16], b.z);
    atomicAdd(&sumsqL[(3 * 16 + t) * 16], b.w);
  }
}

// per-block inline BN-affine from the sums slot
__device__ __forceinline__ void stats_to_lds(
    const float* __restrict__ sumL, const float* __restrict__ sumsqL,
    const float* __restrict__ gamma_l, const float* __restrict__ beta_l,
    float* ms, int t, int n) {
  if (t < 64) {
    float s = sumL[t * 16], sq = sumsqL[t * 16];
    float mu = s / (float)n;
    float var = sq / (float)n - mu * mu;
    float iv = rsqrtf(var + BN_EPS);
    float k1 = iv * gamma_l[t];
    ms[t] = k1;
    ms[64 + t] = beta_l[t] - mu * k1;
  }
  __syncthreads();
}

// hp = dinv * relu(BN(s)): the pre-scaled gather operand for the next layer
__global__ __launch_bounds__(NTHREADS) void k_bnrelu(
    const f16* __restrict__ s, const float* __restrict__ sumL,
    const float* __restrict__ sumsqL, const float* __restrict__ gamma_l,
    const float* __restrict__ beta_l, const float* __restrict__ dinv,
    f16* __restrict__ hp, int n) {
  __shared__ __align__(16) float ms[128];
  int t = threadIdx.x;
  stats_to_lds(sumL, sumsqL, gamma_l, beta_l, ms, t, n);
  int idx = blockIdx.x * NTHREADS + t;  // x4 index
  if (idx < n * (HID / 4)) {
    int c4 = idx & 15;
    int row = idx >> 4;
    f32x4 v = ldh4(s + (size_t)idx * 4);
    f32x4 k1 = *(const f32x4*)(ms + c4 * 4);
    f32x4 k2 = *(const f32x4*)(ms + 64 + c4 * 4);
    v = bnrelu(v, k1, k2);
    float di = dinv[row];
    v = di * v;
    ((f16x4*)hp)[idx] = __builtin_convertvector(v, f16x4);
  }
}

// out = relu(BN_7(s)) @ W_out + b_out   (affine computed inline from slot 7)
__global__ __launch_bounds__(NTHREADS) void k_out(
    const f16* __restrict__ s, const float* __restrict__ sumL,
    const float* __restrict__ sumsqL, const float* __restrict__ gamma_l,
    const float* __restrict__ beta_l, const float* __restrict__ Wout,
    const float* __restrict__ bout, float* __restrict__ out, int n) {
  __shared__ float Ws[HID * OUT_C];
  __shared__ float bs[OUT_C];
  __shared__ __align__(16) float ms[128];
  int t = threadIdx.x;
  for (int m = t; m < HID * OUT_C; m += NTHREADS) Ws[m] = Wout[m];
  if (t < OUT_C) bs[t] = bout[t];
  stats_to_lds(sumL, sumsqL, gamma_l, beta_l, ms, t, n);
  int idx = blockIdx.x * NTHREADS + t;
  if (idx < n * OUT_C) {
    int row = idx / OUT_C;
    int c = idx - row * OUT_C;
    float acc = bs[c];
    const f16* sr = s + (size_t)row * HID;
    for (int kk = 0; kk < HID / 4; kk++) {
      f32x4 a = ldh4(sr + kk * 4);
      f32x4 k1 = *(const f32x4*)(ms + kk * 4);
      f32x4 k2 = *(const f32x4*)(ms + 64 + kk * 4);
      a = bnrelu(a, k1, k2);
      int k = kk * 4;
      acc += a.x * Ws[(k + 0) * OUT_C + c] + a.y * Ws[(k + 1) * OUT_C + c] +
             a.z * Ws[(k + 2) * OUT_C + c] + a.w * Ws[(k + 3) * OUT_C + c];
    }
    out[idx] = acc;
  }
}

// ---------------- host ----------------

extern "C" void kernel_launch(void* const* d_in, const int* in_sizes, int n_in,
                              void* d_out, int out_size, void* d_ws, size_t ws_size,
                              hipStream_t stream) {
  const float* x = (const float*)d_in[0];
  const int* ei = (const int*)d_in[1];
  const float* W0 = (const float*)d_in[2];
  const float* b0 = (const float*)d_in[3];
  const float* convW = (const float*)d_in[4];
  const float* bn_gamma = (const float*)d_in[5];
  const float* bn_beta = (const float*)d_in[6];
  const float* W_out = (const float*)d_in[7];
  const float* b_out = (const float*)d_in[8];
  float* out = (float*)d_out;

  int n = in_sizes[0] / IN_C;   // 100000
  int E = in_sizes[1] / 2;      // 1600000
  const int* row = ei;
  const int* col = ei + E;
  int NB = (n + (1 << BKT_SHIFT) - 1) >> BKT_SHIFT;  // 196 buckets

  char* w = (char*)d_ws;
  auto alloc = [&](size_t bytes) {
    char* p = w;
    w += (bytes + 255) & ~(size_t)255;
    return p;
  };
  float* dinv    = (float*)alloc((size_t)n * 4);
  int*   cnt     = (int*)alloc((size_t)n * 4);
  int*   offs    = (int*)alloc((size_t)(n + 1) * 4);
  int*   cur     = (int*)alloc((size_t)n * 4);
  int*   partials= (int*)alloc(512 * 4);
  int*   bcur    = (int*)alloc(512 * 4);
  int*   ew      = (int*)alloc((size_t)E * 4);          // 4B records
  long long* tmp = (long long*)alloc((size_t)E * 8);    // bucketed (col,row)
  f16*   h016    = (f16*)alloc((size_t)n * HID * 2);
  f16*   hp      = (f16*)alloc((size_t)n * HID * 2);    // dinv * relu(BN(s))
  f16*   sv      = (f16*)alloc((size_t)(n + 16) * HID * 2);  // +16 pad rows
  f16*   sb      = (f16*)alloc((size_t)n * HID * 2);    // conv output s_l
  float* sumP    = (float*)alloc((size_t)N_LAYERS * 1024 * 4);
  float* sumsqP  = (float*)alloc((size_t)N_LAYERS * 1024 * 4);

  int gN = (n + NTHREADS - 1) / NTHREADS;   // 391
  int gE = (E + NTHREADS - 1) / NTHREADS;   // 6250
  int gA = (E + 4095) / 4096;               // 391 (pass A blocks)
  int gRow = (n + 15) / 16;                 // 6250
  int gConv = (gRow + 3) / 4;               // 1563
  int gV = (n * (HID / 4) + NTHREADS - 1) / NTHREADS;

  k_zero<<<gN, NTHREADS, 0, stream>>>(cnt, sumP, sumsqP,
                                      sv + (size_t)n * HID, n);
  k_hist<<<gE, NTHREADS, 0, stream>>>(col, cnt, E);
  k_scan1<<<gN, NTHREADS, 0, stream>>>(cnt, offs, partials, dinv, n);
  k_scan2<<<1, 512, 0, stream>>>(partials, gN);
  k_scan3<<<gN, NTHREADS, 0, stream>>>(offs, cur, partials, bcur, n, E);
  k_bucketA<<<gA, NTHREADS, 0, stream>>>(row, col, bcur, tmp, E, NB);
  k_bucketB<<<NB, NTHREADS, 0, stream>>>(tmp, offs, cur, ew, n);

  k_gemm0<<<512, NTHREADS, 0, stream>>>(x, W0, b0, dinv, h016, hp, n);

  for (int l = 0; l < N_LAYERS; l++) {
    float beta = logf(0.5f / (float)(l + 1) + 1.0f);
    if (l > 0) {  // hp = dinv * relu(BN_{l-1}(s_{l-1})) using slot l-1
      k_bnrelu<<<gV, NTHREADS, 0, stream>>>(
          sb, sumP + (size_t)(l - 1) * 1024, sumsqP + (size_t)(l - 1) * 1024,
          bn_gamma + (l - 1) * HID, bn_beta + (l - 1) * HID, dinv, hp, n);
    }
    k_gather<<<gRow, NTHREADS, 0, stream>>>(hp, h016, dinv, offs, ew, sv, n);
    k_conv<<<gConv, NTHREADS, 0, stream>>>(sv, convW + (size_t)l * HID * HID,
                                           sb, sumP + (size_t)l * 1024,
                                           sumsqP + (size_t)l * 1024, beta, n);
  }

  // s_7 in sb; k_out applies BN_7 (slot 7) + relu inline, then output GEMM
  k_out<<<((size_t)n * OUT_C + NTHREADS - 1) / NTHREADS, NTHREADS, 0, stream>>>(
      sb, sumP + (size_t)7 * 1024, sumsqP + (size_t)7 * 1024,
      bn_gamma + 7 * HID, bn_beta + 7 * HID, W_out, b_out, out, n);
}

// Round 15
// 772.384 us; speedup vs baseline: 1.8014x; 1.7214x over previous
//
#include <hip/hip_runtime.h>
#include <math.h>

#define NTHREADS 256
#define IN_C 128
#define HID 64
#define OUT_C 40
#define N_LAYERS 8
#define ALPHA 0.1f
#define BN_EPS 1e-5f
#define BKT_SHIFT 9   // 512-node buckets for the two-pass CSR fill

typedef float f32x4 __attribute__((ext_vector_type(4)));
typedef _Float16 f16;
typedef _Float16 f16x4 __attribute__((ext_vector_type(4)));
typedef _Float16 f16x8 __attribute__((ext_vector_type(8)));

__device__ __forceinline__ f32x4 ld4(const float* p) { return *(const f32x4*)p; }

__device__ __forceinline__ f32x4 ldh4(const f16* p) {
  f16x4 v = *(const f16x4*)p;
  return __builtin_convertvector(v, f32x4);
}

__device__ __forceinline__ f32x4 bnrelu(f32x4 v, f32x4 k1, f32x4 k2) {
  f32x4 r = v * k1 + k2;
  r.x = fmaxf(r.x, 0.f); r.y = fmaxf(r.y, 0.f);
  r.z = fmaxf(r.z, 0.f); r.w = fmaxf(r.w, 0.f);
  return r;
}

// sum over the 4 16-lane groups (lanes l, l+16, l+32, l+48)
__device__ __forceinline__ f32x4 xreduce(f32x4 v) {
  v.x += __shfl_xor(v.x, 16); v.y += __shfl_xor(v.y, 16);
  v.z += __shfl_xor(v.z, 16); v.w += __shfl_xor(v.w, 16);
  v.x += __shfl_xor(v.x, 32); v.y += __shfl_xor(v.y, 32);
  v.z += __shfl_xor(v.z, 32); v.w += __shfl_xor(v.w, 32);
  return v;
}

// ---------------- setup kernels ----------------

// sums layout: per-layer slot l at [l*1024]; within a slot, partial j
// (j = blockIdx & 15) for channel c lives at [j*64 + c].  16 sub-slots
// spread the BN-stat atomics across 16 different L2 lines per channel
// group (r13: 1563-deep same-address atomic contention was 84 us/layer).
__global__ void k_zero(int* __restrict__ cnt, float* __restrict__ sumP,
                       float* __restrict__ sumsqP, f16* __restrict__ svpad,
                       int n) {
  int i = blockIdx.x * NTHREADS + threadIdx.x;
  if (i < n) cnt[i] = 0;
  if (i < N_LAYERS * 1024) { sumP[i] = 0.f; sumsqP[i] = 0.f; }
  if (i < 256) {  // zero the 16 pad rows of sv (MFMA A-frag tail)
    f16x4 z = {(f16)0.f, (f16)0.f, (f16)0.f, (f16)0.f};
    ((f16x4*)svpad)[i] = z;
  }
}

__global__ void k_hist(const int* __restrict__ col, int* __restrict__ cnt, int E) {
  int e = blockIdx.x * NTHREADS + threadIdx.x;
  if (e < E) atomicAdd(&cnt[col[e]], 1);
}

// scan pass 1 + dinv (deg = cnt + self loop)
__global__ void k_scan1(const int* __restrict__ cnt, int* __restrict__ offs,
                        int* __restrict__ partials, float* __restrict__ dinv,
                        int n) {
  __shared__ int sh[NTHREADS];
  int t = threadIdx.x, i = blockIdx.x * NTHREADS + t;
  int v = (i < n) ? cnt[i] : 0;
  if (i < n) dinv[i] = rsqrtf((float)v + 1.0f);
  sh[t] = v;
  __syncthreads();
  int run = v;
  for (int d = 1; d < NTHREADS; d <<= 1) {
    int add = (t >= d) ? sh[t - d] : 0;
    __syncthreads();
    run += add;
    sh[t] = run;
    __syncthreads();
  }
  if (i < n) offs[i] = run - v;
  if (t == NTHREADS - 1) partials[blockIdx.x] = run;
}

__global__ void k_scan2(int* __restrict__ partials, int nb) {
  __shared__ int sh[512];
  int t = threadIdx.x;
  int v = (t < nb) ? partials[t] : 0;
  sh[t] = v;
  __syncthreads();
  int run = v;
  for (int d = 1; d < 512; d <<= 1) {
    int add = (t >= d) ? sh[t - d] : 0;
    __syncthreads();
    run += add;
    sh[t] = run;
    __syncthreads();
  }
  if (t < nb) partials[t] = run - v;
}

// pass 3: final offs/cur; also seed bucket cursors bcur[b] = offs[b*512]
__global__ void k_scan3(int* __restrict__ offs, int* __restrict__ cur,
                        const int* __restrict__ partials,
                        int* __restrict__ bcur, int n, int E) {
  int i = blockIdx.x * NTHREADS + threadIdx.x;
  if (i < n) {
    int v = offs[i] + partials[i >> 8];
    offs[i] = v;
    cur[i] = v;
    if ((i & ((1 << BKT_SHIFT) - 1)) == 0) bcur[i >> BKT_SHIFT] = v;
  }
  if (i == 0) offs[n] = E;
}

// ---- bucketed CSR fill, pass A: scatter (col,row) into 32KB bucket regions.
__global__ __launch_bounds__(NTHREADS) void k_bucketA(
    const int* __restrict__ row, const int* __restrict__ col,
    int* __restrict__ bcur, long long* __restrict__ tmp, int E, int nb) {
  __shared__ int lhist[512];
  __shared__ int lbase[512];
  int t = threadIdx.x;
  for (int i = t; i < nb; i += NTHREADS) lhist[i] = 0;
  __syncthreads();
  int start = blockIdx.x * 4096;
  int end = min(E, start + 4096);
  for (int e = start + t; e < end; e += NTHREADS)
    atomicAdd(&lhist[col[e] >> BKT_SHIFT], 1);
  __syncthreads();
  for (int i = t; i < nb; i += NTHREADS) {
    int c = lhist[i];
    lbase[i] = c ? atomicAdd(&bcur[i], c) : 0;
    lhist[i] = 0;
  }
  __syncthreads();
  for (int e = start + t; e < end; e += NTHREADS) {
    int cl = col[e];
    int b = cl >> BKT_SHIFT;
    int slot = atomicAdd(&lhist[b], 1);
    tmp[lbase[b] + slot] = ((long long)cl << 32) | (unsigned int)row[e];
  }
}

// ---- pass B: one block per bucket; stream the region, place records at
// final CSR positions (all inside the same ~32KB window).
__global__ __launch_bounds__(NTHREADS) void k_bucketB(
    const long long* __restrict__ tmp, const int* __restrict__ offs,
    int* __restrict__ cur, int* __restrict__ ew, int n) {
  int b = blockIdx.x;
  int lo = b << BKT_SHIFT;
  int hi = min(n, lo + (1 << BKT_SHIFT));
  int s = offs[lo], e2 = offs[hi];
  for (int j = s + threadIdx.x; j < e2; j += NTHREADS) {
    long long r = tmp[j];
    int cl = (int)(r >> 32);
    int rw = (int)(r & 0xffffffffLL);
    int pos = atomicAdd(&cur[cl], 1);
    ew[pos] = rw;
  }
}

// ---------------- MFMA gemm0: h0 = relu(x@W0+b0), hp = dinv*h0 ----------------
__global__ void k_gemm0(
    const float* __restrict__ x, const float* __restrict__ W0,
    const float* __restrict__ b0, const float* __restrict__ dinv,
    f16* __restrict__ h016, f16* __restrict__ hp, int n) {
  int t = threadIdx.x;
  int lane = t & 63, wid = t >> 6;
  int lm = lane & 15, lk = lane >> 4;
  f16x8 bf[4][4];
  float bv[4];
#pragma unroll
  for (int nt = 0; nt < 4; nt++) {
    int c = nt * 16 + lm;
    bv[nt] = b0[c];
#pragma unroll
    for (int ks = 0; ks < 4; ks++) {
#pragma unroll
      for (int i = 0; i < 8; i++) {
        bf[nt][ks][i] = (f16)W0[(ks * 32 + lk * 8 + i) * HID + c];
      }
    }
  }
  int nblk = (n + 15) >> 4;
  for (int blk = blockIdx.x * 4 + wid; blk < nblk; blk += gridDim.x * 4) {
    int r0 = blk * 16;
    int rA = min(r0 + lm, n - 1);
    const float* xr = x + (size_t)rA * IN_C + lk * 8;
    f16x8 af[4];
#pragma unroll
    for (int ks = 0; ks < 4; ks++) {
      f32x4 lo = ld4(xr + ks * 32);
      f32x4 hi = ld4(xr + ks * 32 + 4);
      f16x4 l16 = __builtin_convertvector(lo, f16x4);
      f16x4 h16 = __builtin_convertvector(hi, f16x4);
#pragma unroll
      for (int i = 0; i < 4; i++) { af[ks][i] = l16[i]; af[ks][4 + i] = h16[i]; }
    }
    float dv[4];
#pragma unroll
    for (int reg = 0; reg < 4; reg++)
      dv[reg] = dinv[min(r0 + lk * 4 + reg, n - 1)];
#pragma unroll
    for (int nt = 0; nt < 4; nt++) {
      f32x4 z = {0.f, 0.f, 0.f, 0.f};
      z = __builtin_amdgcn_mfma_f32_16x16x32_f16(af[0], bf[nt][0], z, 0, 0, 0);
      z = __builtin_amdgcn_mfma_f32_16x16x32_f16(af[1], bf[nt][1], z, 0, 0, 0);
      z = __builtin_amdgcn_mfma_f32_16x16x32_f16(af[2], bf[nt][2], z, 0, 0, 0);
      z = __builtin_amdgcn_mfma_f32_16x16x32_f16(af[3], bf[nt][3], z, 0, 0, 0);
#pragma unroll
      for (int reg = 0; reg < 4; reg++) {
        int r = r0 + lk * 4 + reg;
        if (r < n) {
          float v = fmaxf(z[reg] + bv[nt], 0.f);
          h016[(size_t)r * HID + nt * 16 + lm] = (f16)v;
          hp[(size_t)r * HID + nt * 16 + lm] = (f16)(dv[reg] * v);
        }
      }
    }
  }
}

// ---------------- gather-only kernel (barrier-free) ----------
// sv[i] = (1-a)*di*(acc + hp[i]) + a*h0[i],   acc = sum_j hp[src_j]
__global__ void k_gather(
    const f16* __restrict__ hp, const f16* __restrict__ h0,
    const float* __restrict__ dinv, const int* __restrict__ offs,
    const int* __restrict__ ew, f16* __restrict__ sv, int n) {
  int t = threadIdx.x;
  int lane = t & 63;
  int eg = lane >> 4, li = lane & 15, c4 = li << 2;
  int i = blockIdx.x * 16 + (t >> 6) * 4 + eg;  // this group's row
  if (i >= n) return;
  int jb = offs[i], je = offs[i + 1];
  float di = dinv[i];
  f16x4 hs16 = *(const f16x4*)(hp + (size_t)i * HID + c4);
  f16x4 h016v = *(const f16x4*)(h0 + (size_t)i * HID + c4);
  f32x4 acc = {0.f, 0.f, 0.f, 0.f};
  int j = jb;
  for (; j + 8 <= je; j += 8) {
    int q0 = ew[j + 0];
    int q1 = ew[j + 1];
    int q2 = ew[j + 2];
    int q3 = ew[j + 3];
    int q4 = ew[j + 4];
    int q5 = ew[j + 5];
    int q6 = ew[j + 6];
    int q7 = ew[j + 7];
    f16x4 u0 = *(const f16x4*)(hp + (size_t)q0 * HID + c4);
    f16x4 u1 = *(const f16x4*)(hp + (size_t)q1 * HID + c4);
    f16x4 u2 = *(const f16x4*)(hp + (size_t)q2 * HID + c4);
    f16x4 u3 = *(const f16x4*)(hp + (size_t)q3 * HID + c4);
    f16x4 u4 = *(const f16x4*)(hp + (size_t)q4 * HID + c4);
    f16x4 u5 = *(const f16x4*)(hp + (size_t)q5 * HID + c4);
    f16x4 u6 = *(const f16x4*)(hp + (size_t)q6 * HID + c4);
    f16x4 u7 = *(const f16x4*)(hp + (size_t)q7 * HID + c4);
    acc += __builtin_convertvector(u0, f32x4);
    acc += __builtin_convertvector(u1, f32x4);
    acc += __builtin_convertvector(u2, f32x4);
    acc += __builtin_convertvector(u3, f32x4);
    acc += __builtin_convertvector(u4, f32x4);
    acc += __builtin_convertvector(u5, f32x4);
    acc += __builtin_convertvector(u6, f32x4);
    acc += __builtin_convertvector(u7, f32x4);
  }
  for (; j < je; j++) {
    acc += ldh4(hp + (size_t)ew[j] * HID + c4);
  }
  f32x4 hs = __builtin_convertvector(hs16, f32x4);
  f32x4 h0v = __builtin_convertvector(h016v, f32x4);
  f32x4 sval = (1.f - ALPHA) * (di * (acc + hs)) + ALPHA * h0v;
  *(f16x4*)(sv + (size_t)i * HID + c4) = __builtin_convertvector(sval, f16x4);
}

// ---------------- MFMA conv + BN stats (atomics spread over 16 sub-slots) ---
// S2 = SV @ W',  W' = (1-beta)I + beta*W (built during LDS staging, fp16).
__global__ __launch_bounds__(NTHREADS) void k_conv(
    const f16* __restrict__ sv, const float* __restrict__ Wl,
    f16* __restrict__ sout, float* __restrict__ sumL,
    float* __restrict__ sumsqL, float beta, int n) {
  __shared__ __align__(16) float Wsh[HID * HID];  // W' staged, 16 KB
  __shared__ f32x4 red4[2][4][16];
  int t = threadIdx.x;
  // stage W' = beta*W + (1-beta)*I
  for (int m = t; m < HID * HID / 4; m += NTHREADS) {
    f32x4 wv = ((const f32x4*)Wl)[m];
    wv *= beta;
    int base = m * 4;
    int k = base >> 6, c0 = base & 63;
    if (k >= c0 && k < c0 + 4) wv[k - c0] += (1.f - beta);
    ((f32x4*)Wsh)[m] = wv;
  }
  __syncthreads();
  int lane = t & 63, wid = t >> 6;
  int lm = lane & 15, lk = lane >> 4;
  // B fragments: 4 col-tiles x 2 K-steps, cast to fp16
  f16x8 bf[4][2];
#pragma unroll
  for (int nt = 0; nt < 4; nt++) {
#pragma unroll
    for (int ks = 0; ks < 2; ks++) {
      int c = nt * 16 + lm;
#pragma unroll
      for (int i = 0; i < 8; i++) {
        int k = ks * 32 + lk * 8 + i;
        bf[nt][ks][i] = (f16)Wsh[k * HID + c];
      }
    }
  }
  float ssum[4] = {0.f, 0.f, 0.f, 0.f}, ssq[4] = {0.f, 0.f, 0.f, 0.f};
  int nblk = (n + 15) >> 4;
  for (int blk = blockIdx.x * 4 + wid; blk < nblk; blk += gridDim.x * 4) {
    int r0 = blk * 16;
    const f16* ap = sv + (size_t)(r0 + lm) * HID + lk * 8;  // pad rows zeroed
    f16x8 a0 = *(const f16x8*)(ap);
    f16x8 a1 = *(const f16x8*)(ap + 32);
#pragma unroll
    for (int nt = 0; nt < 4; nt++) {
      f32x4 z = {0.f, 0.f, 0.f, 0.f};
      z = __builtin_amdgcn_mfma_f32_16x16x32_f16(a0, bf[nt][0], z, 0, 0, 0);
      z = __builtin_amdgcn_mfma_f32_16x16x32_f16(a1, bf[nt][1], z, 0, 0, 0);
#pragma unroll
      for (int reg = 0; reg < 4; reg++) {
        int r = r0 + lk * 4 + reg;
        if (r < n) {
          float v = z[reg];
          sout[(size_t)r * HID + nt * 16 + lm] = (f16)v;
          ssum[nt] += v;
          ssq[nt] += v * v;
        }
      }
    }
  }
  // stats reduce: lanes l, l+16, l+32, l+48 share the same channel set
  f32x4 sumv = {ssum[0], ssum[1], ssum[2], ssum[3]};
  f32x4 sqv = {ssq[0], ssq[1], ssq[2], ssq[3]};
  sumv = xreduce(sumv);
  sqv = xreduce(sqv);
  if (lk == 0) { red4[0][wid][lm] = sumv; red4[1][wid][lm] = sqv; }
  __syncthreads();
  if (t < 16) {
    f32x4 a = red4[0][0][t] + red4[0][1][t] + red4[0][2][t] + red4[0][3][t];
    f32x4 b = red4[1][0][t] + red4[1][1][t] + red4[1][2][t] + red4[1][3][t];
    int js = (blockIdx.x & 15) * 64;  // per-block sub-slot: distinct L2 lines
    atomicAdd(&sumL[js + 0 * 16 + t], a.x);
    atomicAdd(&sumL[js + 1 * 16 + t], a.y);
    atomicAdd(&sumL[js + 2 * 16 + t], a.z);
    atomicAdd(&sumL[js + 3 * 16 + t], a.w);
    atomicAdd(&sumsqL[js + 0 * 16 + t], b.x);
    atomicAdd(&sumsqL[js + 1 * 16 + t], b.y);
    atomicAdd(&sumsqL[js + 2 * 16 + t], b.z);
    atomicAdd(&sumsqL[js + 3 * 16 + t], b.w);
  }
}

// per-block inline BN-affine from the sums slot (sums 16 sub-slots)
__device__ __forceinline__ void stats_to_lds(
    const float* __restrict__ sumL, const float* __restrict__ sumsqL,
    const float* __restrict__ gamma_l, const float* __restrict__ beta_l,
    float* ms, int t, int n) {
  if (t < 64) {
    float s = 0.f, sq = 0.f;
#pragma unroll
    for (int j = 0; j < 16; j++) {
      s += sumL[j * 64 + t];
      sq += sumsqL[j * 64 + t];
    }
    float mu = s / (float)n;
    float var = sq / (float)n - mu * mu;
    float iv = rsqrtf(var + BN_EPS);
    float k1 = iv * gamma_l[t];
    ms[t] = k1;
    ms[64 + t] = beta_l[t] - mu * k1;
  }
  __syncthreads();
}

// hp = dinv * relu(BN(s)): the pre-scaled gather operand for the next layer
__global__ __launch_bounds__(NTHREADS) void k_bnrelu(
    const f16* __restrict__ s, const float* __restrict__ sumL,
    const float* __restrict__ sumsqL, const float* __restrict__ gamma_l,
    const float* __restrict__ beta_l, const float* __restrict__ dinv,
    f16* __restrict__ hp, int n) {
  __shared__ __align__(16) float ms[128];
  int t = threadIdx.x;
  stats_to_lds(sumL, sumsqL, gamma_l, beta_l, ms, t, n);
  int idx = blockIdx.x * NTHREADS + t;  // x4 index
  if (idx < n * (HID / 4)) {
    int c4 = idx & 15;
    int row = idx >> 4;
    f32x4 v = ldh4(s + (size_t)idx * 4);
    f32x4 k1 = *(const f32x4*)(ms + c4 * 4);
    f32x4 k2 = *(const f32x4*)(ms + 64 + c4 * 4);
    v = bnrelu(v, k1, k2);
    float di = dinv[row];
    v = di * v;
    ((f16x4*)hp)[idx] = __builtin_convertvector(v, f16x4);
  }
}

// out = relu(BN_7(s)) @ W_out + b_out   (affine computed inline from slot 7)
__global__ __launch_bounds__(NTHREADS) void k_out(
    const f16* __restrict__ s, const float* __restrict__ sumL,
    const float* __restrict__ sumsqL, const float* __restrict__ gamma_l,
    const float* __restrict__ beta_l, const float* __restrict__ Wout,
    const float* __restrict__ bout, float* __restrict__ out, int n) {
  __shared__ float Ws[HID * OUT_C];
  __shared__ float bs[OUT_C];
  __shared__ __align__(16) float ms[128];
  int t = threadIdx.x;
  for (int m = t; m < HID * OUT_C; m += NTHREADS) Ws[m] = Wout[m];
  if (t < OUT_C) bs[t] = bout[t];
  stats_to_lds(sumL, sumsqL, gamma_l, beta_l, ms, t, n);
  int idx = blockIdx.x * NTHREADS + t;
  if (idx < n * OUT_C) {
    int row = idx / OUT_C;
    int c = idx - row * OUT_C;
    float acc = bs[c];
    const f16* sr = s + (size_t)row * HID;
    for (int kk = 0; kk < HID / 4; kk++) {
      f32x4 a = ldh4(sr + kk * 4);
      f32x4 k1 = *(const f32x4*)(ms + kk * 4);
      f32x4 k2 = *(const f32x4*)(ms + 64 + kk * 4);
      a = bnrelu(a, k1, k2);
      int k = kk * 4;
      acc += a.x * Ws[(k + 0) * OUT_C + c] + a.y * Ws[(k + 1) * OUT_C + c] +
             a.z * Ws[(k + 2) * OUT_C + c] + a.w * Ws[(k + 3) * OUT_C + c];
    }
    out[idx] = acc;
  }
}

// ---------------- host ----------------

extern "C" void kernel_launch(void* const* d_in, const int* in_sizes, int n_in,
                              void* d_out, int out_size, void* d_ws, size_t ws_size,
                              hipStream_t stream) {
  const float* x = (const float*)d_in[0];
  const int* ei = (const int*)d_in[1];
  const float* W0 = (const float*)d_in[2];
  const float* b0 = (const float*)d_in[3];
  const float* convW = (const float*)d_in[4];
  const float* bn_gamma = (const float*)d_in[5];
  const float* bn_beta = (const float*)d_in[6];
  const float* W_out = (const float*)d_in[7];
  const float* b_out = (const float*)d_in[8];
  float* out = (float*)d_out;

  int n = in_sizes[0] / IN_C;   // 100000
  int E = in_sizes[1] / 2;      // 1600000
  const int* row = ei;
  const int* col = ei + E;
  int NB = (n + (1 << BKT_SHIFT) - 1) >> BKT_SHIFT;  // 196 buckets

  char* w = (char*)d_ws;
  auto alloc = [&](size_t bytes) {
    char* p = w;
    w += (bytes + 255) & ~(size_t)255;
    return p;
  };
  float* dinv    = (float*)alloc((size_t)n * 4);
  int*   cnt     = (int*)alloc((size_t)n * 4);
  int*   offs    = (int*)alloc((size_t)(n + 1) * 4);
  int*   cur     = (int*)alloc((size_t)n * 4);
  int*   partials= (int*)alloc(512 * 4);
  int*   bcur    = (int*)alloc(512 * 4);
  int*   ew      = (int*)alloc((size_t)E * 4);          // 4B records
  long long* tmp = (long long*)alloc((size_t)E * 8);    // bucketed (col,row)
  f16*   h016    = (f16*)alloc((size_t)n * HID * 2);
  f16*   hp      = (f16*)alloc((size_t)n * HID * 2);    // dinv * relu(BN(s))
  f16*   sv      = (f16*)alloc((size_t)(n + 16) * HID * 2);  // +16 pad rows
  f16*   sb      = (f16*)alloc((size_t)n * HID * 2);    // conv output s_l
  float* sumP    = (float*)alloc((size_t)N_LAYERS * 1024 * 4);
  float* sumsqP  = (float*)alloc((size_t)N_LAYERS * 1024 * 4);

  int gN = (n + NTHREADS - 1) / NTHREADS;   // 391
  int gE = (E + NTHREADS - 1) / NTHREADS;   // 6250
  int gA = (E + 4095) / 4096;               // 391 (pass A blocks)
  int gRow = (n + 15) / 16;                 // 6250
  int gConv = (gRow + 3) / 4;               // 1563
  int gV = (n * (HID / 4) + NTHREADS - 1) / NTHREADS;

  k_zero<<<gN, NTHREADS, 0, stream>>>(cnt, sumP, sumsqP,
                                      sv + (size_t)n * HID, n);
  k_hist<<<gE, NTHREADS, 0, stream>>>(col, cnt, E);
  k_scan1<<<gN, NTHREADS, 0, stream>>>(cnt, offs, partials, dinv, n);
  k_scan2<<<1, 512, 0, stream>>>(partials, gN);
  k_scan3<<<gN, NTHREADS, 0, stream>>>(offs, cur, partials, bcur, n, E);
  k_bucketA<<<gA, NTHREADS, 0, stream>>>(row, col, bcur, tmp, E, NB);
  k_bucketB<<<NB, NTHREADS, 0, stream>>>(tmp, offs, cur, ew, n);

  k_gemm0<<<512, NTHREADS, 0, stream>>>(x, W0, b0, dinv, h016, hp, n);

  for (int l = 0; l < N_LAYERS; l++) {
    float beta = logf(0.5f / (float)(l + 1) + 1.0f);
    if (l > 0) {  // hp = dinv * relu(BN_{l-1}(s_{l-1})) using slot l-1
      k_bnrelu<<<gV, NTHREADS, 0, stream>>>(
          sb, sumP + (size_t)(l - 1) * 1024, sumsqP + (size_t)(l - 1) * 1024,
          bn_gamma + (l - 1) * HID, bn_beta + (l - 1) * HID, dinv, hp, n);
    }
    k_gather<<<gRow, NTHREADS, 0, stream>>>(hp, h016, dinv, offs, ew, sv, n);
    k_conv<<<gConv, NTHREADS, 0, stream>>>(sv, convW + (size_t)l * HID * HID,
                                           sb, sumP + (size_t)l * 1024,
                                           sumsqP + (size_t)l * 1024, beta, n);
  }

  // s_7 in sb; k_out applies BN_7 (slot 7) + relu inline, then output GEMM
  k_out<<<((size_t)n * OUT_C + NTHREADS - 1) / NTHREADS, NTHREADS, 0, stream>>>(
      sb, sumP + (size_t)7 * 1024, sumsqP + (size_t)7 * 1024,
      bn_gamma + 7 * HID, bn_beta + 7 * HID, W_out, b_out, out, n);
}

// Round 16
// 693.140 us; speedup vs baseline: 2.0073x; 1.1143x over previous
//
#include <hip/hip_runtime.h>
#include <math.h>

#define NTHREADS 256
#define IN_C 128
#define HID 64
#define OUT_C 40
#define N_LAYERS 8
#define ALPHA 0.1f
#define BN_EPS 1e-5f
#define BKT_SHIFT 9   // 512-node buckets for the CSR build

typedef float f32x4 __attribute__((ext_vector_type(4)));
typedef _Float16 f16;
typedef _Float16 f16x4 __attribute__((ext_vector_type(4)));
typedef _Float16 f16x8 __attribute__((ext_vector_type(8)));

__device__ __forceinline__ f32x4 ld4(const float* p) { return *(const f32x4*)p; }

__device__ __forceinline__ f32x4 ldh4(const f16* p) {
  f16x4 v = *(const f16x4*)p;
  return __builtin_convertvector(v, f32x4);
}

__device__ __forceinline__ f32x4 bnrelu(f32x4 v, f32x4 k1, f32x4 k2) {
  f32x4 r = v * k1 + k2;
  r.x = fmaxf(r.x, 0.f); r.y = fmaxf(r.y, 0.f);
  r.z = fmaxf(r.z, 0.f); r.w = fmaxf(r.w, 0.f);
  return r;
}

// sum over the 4 16-lane groups (lanes l, l+16, l+32, l+48)
__device__ __forceinline__ f32x4 xreduce(f32x4 v) {
  v.x += __shfl_xor(v.x, 16); v.y += __shfl_xor(v.y, 16);
  v.z += __shfl_xor(v.z, 16); v.w += __shfl_xor(v.w, 16);
  v.x += __shfl_xor(v.x, 32); v.y += __shfl_xor(v.y, 32);
  v.z += __shfl_xor(v.z, 32); v.w += __shfl_xor(v.w, 32);
  return v;
}

// ---------------- setup kernels ----------------

// sums layout: per-layer slot l at [l*1024]; sub-slot j (= blockIdx & 15)
// for channel c at [j*64 + c] (r14: spreads BN-stat atomic contention).
__global__ void k_zero(float* __restrict__ sumP, float* __restrict__ sumsqP,
                       f16* __restrict__ svpad, int* __restrict__ bcnt) {
  int i = blockIdx.x * NTHREADS + threadIdx.x;
  if (i < N_LAYERS * 1024) { sumP[i] = 0.f; sumsqP[i] = 0.f; }
  if (i < 256) {  // zero the 16 pad rows of sv (MFMA A-frag tail)
    f16x4 z = {(f16)0.f, (f16)0.f, (f16)0.f, (f16)0.f};
    ((f16x4*)svpad)[i] = z;
  }
  if (blockIdx.x == 0 && threadIdx.x < 256) bcnt[threadIdx.x] = 0;
}

// 196-bucket histogram of col: LDS-aggregated, one global atomic per
// (block,bucket) — no per-node atomics (r15: k_hist's 1.6M random atomics
// were 65 us + 50 MB of sector-RMW writes).
__global__ __launch_bounds__(NTHREADS) void k_bhist(
    const int* __restrict__ col, int* __restrict__ bcnt, int E, int nb) {
  __shared__ int lhist[512];
  int t = threadIdx.x;
  for (int i = t; i < nb; i += NTHREADS) lhist[i] = 0;
  __syncthreads();
  int start = blockIdx.x * 4096;
  int end = min(E, start + 4096);
  for (int e = start + t; e < end; e += NTHREADS)
    atomicAdd(&lhist[col[e] >> BKT_SHIFT], 1);
  __syncthreads();
  for (int i = t; i < nb; i += NTHREADS) {
    int c = lhist[i];
    if (c) atomicAdd(&bcnt[i], c);
  }
}

// 1-block scan of bucket totals -> bbase (exclusive), bcur seed, offs[n]=E
__global__ void k_bscan(const int* __restrict__ bcnt, int* __restrict__ bbase,
                        int* __restrict__ bcur, int* __restrict__ offs,
                        int nb, int n, int E) {
  __shared__ int sh[256];
  int t = threadIdx.x;  // 256 threads, nb <= 256
  int v = (t < nb) ? bcnt[t] : 0;
  sh[t] = v;
  __syncthreads();
  int run = v;
  for (int d = 1; d < 256; d <<= 1) {
    int add = (t >= d) ? sh[t - d] : 0;
    __syncthreads();
    run += add;
    sh[t] = run;
    __syncthreads();
  }
  if (t < nb) {
    bbase[t] = run - v;
    bcur[t] = run - v;
  }
  if (t == 0) {
    bbase[nb] = E;
    offs[n] = E;
  }
}

// pass A: scatter (col,row) into contiguous bucket regions (L2-local).
__global__ __launch_bounds__(NTHREADS) void k_bucketA(
    const int* __restrict__ row, const int* __restrict__ col,
    int* __restrict__ bcur, long long* __restrict__ tmp, int E, int nb) {
  __shared__ int lhist[512];
  __shared__ int lbase[512];
  int t = threadIdx.x;
  for (int i = t; i < nb; i += NTHREADS) lhist[i] = 0;
  __syncthreads();
  int start = blockIdx.x * 4096;
  int end = min(E, start + 4096);
  for (int e = start + t; e < end; e += NTHREADS)
    atomicAdd(&lhist[col[e] >> BKT_SHIFT], 1);
  __syncthreads();
  for (int i = t; i < nb; i += NTHREADS) {
    int c = lhist[i];
    lbase[i] = c ? atomicAdd(&bcur[i], c) : 0;
    lhist[i] = 0;
  }
  __syncthreads();
  for (int e = start + t; e < end; e += NTHREADS) {
    int cl = col[e];
    int b = cl >> BKT_SHIFT;
    int slot = atomicAdd(&lhist[b], 1);
    tmp[lbase[b] + slot] = ((long long)cl << 32) | (unsigned int)row[e];
  }
}

// pass B (512 threads): per bucket — LDS per-node counts, LDS scan, write
// offs/dinv densely, then place records via LDS cursors. ZERO global atomics.
__global__ __launch_bounds__(512) void k_bucketB(
    const long long* __restrict__ tmp, const int* __restrict__ bbase,
    int* __restrict__ offs, float* __restrict__ dinv,
    int* __restrict__ ew, int n) {
  __shared__ int lcnt[512];
  __shared__ int lcur[512];
  int b = blockIdx.x;
  int t = threadIdx.x;
  int lo = b << BKT_SHIFT;
  int s = bbase[b], e2 = bbase[b + 1];
  lcnt[t] = 0;
  __syncthreads();
  for (int j = s + t; j < e2; j += 512)
    atomicAdd(&lcnt[(int)(tmp[j] >> 32) - lo], 1);
  __syncthreads();
  int v = lcnt[t];
  int run = v;
  for (int d = 1; d < 512; d <<= 1) {
    int add = (t >= d) ? lcnt[t - d] : 0;
    __syncthreads();
    run += add;
    lcnt[t] = run;
    __syncthreads();
  }
  int node = lo + t;
  int myoff = s + run - v;  // exclusive position of this node's edge list
  if (node < n) {
    offs[node] = myoff;
    dinv[node] = rsqrtf((float)v + 1.0f);
  }
  lcur[t] = myoff;
  __syncthreads();
  for (int j = s + t; j < e2; j += 512) {
    long long r = tmp[j];
    int cl = (int)(r >> 32);
    int pos = atomicAdd(&lcur[cl - lo], 1);  // LDS atomic
    ew[pos] = (int)(r & 0xffffffffLL);
  }
}

// ---------------- MFMA gemm0: h0 = relu(x@W0+b0), hp = dinv*h0 ----------------
__global__ void k_gemm0(
    const float* __restrict__ x, const float* __restrict__ W0,
    const float* __restrict__ b0, const float* __restrict__ dinv,
    f16* __restrict__ h016, f16* __restrict__ hp, int n) {
  int t = threadIdx.x;
  int lane = t & 63, wid = t >> 6;
  int lm = lane & 15, lk = lane >> 4;
  f16x8 bf[4][4];
  float bv[4];
#pragma unroll
  for (int nt = 0; nt < 4; nt++) {
    int c = nt * 16 + lm;
    bv[nt] = b0[c];
#pragma unroll
    for (int ks = 0; ks < 4; ks++) {
#pragma unroll
      for (int i = 0; i < 8; i++) {
        bf[nt][ks][i] = (f16)W0[(ks * 32 + lk * 8 + i) * HID + c];
      }
    }
  }
  int nblk = (n + 15) >> 4;
  for (int blk = blockIdx.x * 4 + wid; blk < nblk; blk += gridDim.x * 4) {
    int r0 = blk * 16;
    int rA = min(r0 + lm, n - 1);
    const float* xr = x + (size_t)rA * IN_C + lk * 8;
    f16x8 af[4];
#pragma unroll
    for (int ks = 0; ks < 4; ks++) {
      f32x4 lo = ld4(xr + ks * 32);
      f32x4 hi = ld4(xr + ks * 32 + 4);
      f16x4 l16 = __builtin_convertvector(lo, f16x4);
      f16x4 h16 = __builtin_convertvector(hi, f16x4);
#pragma unroll
      for (int i = 0; i < 4; i++) { af[ks][i] = l16[i]; af[ks][4 + i] = h16[i]; }
    }
    float dv[4];
#pragma unroll
    for (int reg = 0; reg < 4; reg++)
      dv[reg] = dinv[min(r0 + lk * 4 + reg, n - 1)];
#pragma unroll
    for (int nt = 0; nt < 4; nt++) {
      f32x4 z = {0.f, 0.f, 0.f, 0.f};
      z = __builtin_amdgcn_mfma_f32_16x16x32_f16(af[0], bf[nt][0], z, 0, 0, 0);
      z = __builtin_amdgcn_mfma_f32_16x16x32_f16(af[1], bf[nt][1], z, 0, 0, 0);
      z = __builtin_amdgcn_mfma_f32_16x16x32_f16(af[2], bf[nt][2], z, 0, 0, 0);
      z = __builtin_amdgcn_mfma_f32_16x16x32_f16(af[3], bf[nt][3], z, 0, 0, 0);
#pragma unroll
      for (int reg = 0; reg < 4; reg++) {
        int r = r0 + lk * 4 + reg;
        if (r < n) {
          float v = fmaxf(z[reg] + bv[nt], 0.f);
          h016[(size_t)r * HID + nt * 16 + lm] = (f16)v;
          hp[(size_t)r * HID + nt * 16 + lm] = (f16)(dv[reg] * v);
        }
      }
    }
  }
}

// ---------------- gather-only kernel (barrier-free) ----------
// sv[i] = (1-a)*di*(acc + hp[i]) + a*h0[i],   acc = sum_j hp[src_j]
__global__ void k_gather(
    const f16* __restrict__ hp, const f16* __restrict__ h0,
    const float* __restrict__ dinv, const int* __restrict__ offs,
    const int* __restrict__ ew, f16* __restrict__ sv, int n) {
  int t = threadIdx.x;
  int lane = t & 63;
  int eg = lane >> 4, li = lane & 15, c4 = li << 2;
  int i = blockIdx.x * 16 + (t >> 6) * 4 + eg;  // this group's row
  if (i >= n) return;
  int jb = offs[i], je = offs[i + 1];
  float di = dinv[i];
  f16x4 hs16 = *(const f16x4*)(hp + (size_t)i * HID + c4);
  f16x4 h016v = *(const f16x4*)(h0 + (size_t)i * HID + c4);
  f32x4 acc = {0.f, 0.f, 0.f, 0.f};
  int j = jb;
  for (; j + 8 <= je; j += 8) {
    int q0 = ew[j + 0];
    int q1 = ew[j + 1];
    int q2 = ew[j + 2];
    int q3 = ew[j + 3];
    int q4 = ew[j + 4];
    int q5 = ew[j + 5];
    int q6 = ew[j + 6];
    int q7 = ew[j + 7];
    f16x4 u0 = *(const f16x4*)(hp + (size_t)q0 * HID + c4);
    f16x4 u1 = *(const f16x4*)(hp + (size_t)q1 * HID + c4);
    f16x4 u2 = *(const f16x4*)(hp + (size_t)q2 * HID + c4);
    f16x4 u3 = *(const f16x4*)(hp + (size_t)q3 * HID + c4);
    f16x4 u4 = *(const f16x4*)(hp + (size_t)q4 * HID + c4);
    f16x4 u5 = *(const f16x4*)(hp + (size_t)q5 * HID + c4);
    f16x4 u6 = *(const f16x4*)(hp + (size_t)q6 * HID + c4);
    f16x4 u7 = *(const f16x4*)(hp + (size_t)q7 * HID + c4);
    acc += __builtin_convertvector(u0, f32x4);
    acc += __builtin_convertvector(u1, f32x4);
    acc += __builtin_convertvector(u2, f32x4);
    acc += __builtin_convertvector(u3, f32x4);
    acc += __builtin_convertvector(u4, f32x4);
    acc += __builtin_convertvector(u5, f32x4);
    acc += __builtin_convertvector(u6, f32x4);
    acc += __builtin_convertvector(u7, f32x4);
  }
  for (; j < je; j++) {
    acc += ldh4(hp + (size_t)ew[j] * HID + c4);
  }
  f32x4 hs = __builtin_convertvector(hs16, f32x4);
  f32x4 h0v = __builtin_convertvector(h016v, f32x4);
  f32x4 sval = (1.f - ALPHA) * (di * (acc + hs)) + ALPHA * h0v;
  *(f16x4*)(sv + (size_t)i * HID + c4) = __builtin_convertvector(sval, f16x4);
}

// ---------------- MFMA conv + BN stats (atomics spread over 16 sub-slots) ---
// S2 = SV @ W',  W' = (1-beta)I + beta*W (built during LDS staging, fp16).
__global__ __launch_bounds__(NTHREADS) void k_conv(
    const f16* __restrict__ sv, const float* __restrict__ Wl,
    f16* __restrict__ sout, float* __restrict__ sumL,
    float* __restrict__ sumsqL, float beta, int n) {
  __shared__ __align__(16) float Wsh[HID * HID];  // W' staged, 16 KB
  __shared__ f32x4 red4[2][4][16];
  int t = threadIdx.x;
  // stage W' = beta*W + (1-beta)*I
  for (int m = t; m < HID * HID / 4; m += NTHREADS) {
    f32x4 wv = ((const f32x4*)Wl)[m];
    wv *= beta;
    int base = m * 4;
    int k = base >> 6, c0 = base & 63;
    if (k >= c0 && k < c0 + 4) wv[k - c0] += (1.f - beta);
    ((f32x4*)Wsh)[m] = wv;
  }
  __syncthreads();
  int lane = t & 63, wid = t >> 6;
  int lm = lane & 15, lk = lane >> 4;
  // B fragments: 4 col-tiles x 2 K-steps, cast to fp16
  f16x8 bf[4][2];
#pragma unroll
  for (int nt = 0; nt < 4; nt++) {
#pragma unroll
    for (int ks = 0; ks < 2; ks++) {
      int c = nt * 16 + lm;
#pragma unroll
      for (int i = 0; i < 8; i++) {
        int k = ks * 32 + lk * 8 + i;
        bf[nt][ks][i] = (f16)Wsh[k * HID + c];
      }
    }
  }
  float ssum[4] = {0.f, 0.f, 0.f, 0.f}, ssq[4] = {0.f, 0.f, 0.f, 0.f};
  int nblk = (n + 15) >> 4;
  for (int blk = blockIdx.x * 4 + wid; blk < nblk; blk += gridDim.x * 4) {
    int r0 = blk * 16;
    const f16* ap = sv + (size_t)(r0 + lm) * HID + lk * 8;  // pad rows zeroed
    f16x8 a0 = *(const f16x8*)(ap);
    f16x8 a1 = *(const f16x8*)(ap + 32);
#pragma unroll
    for (int nt = 0; nt < 4; nt++) {
      f32x4 z = {0.f, 0.f, 0.f, 0.f};
      z = __builtin_amdgcn_mfma_f32_16x16x32_f16(a0, bf[nt][0], z, 0, 0, 0);
      z = __builtin_amdgcn_mfma_f32_16x16x32_f16(a1, bf[nt][1], z, 0, 0, 0);
#pragma unroll
      for (int reg = 0; reg < 4; reg++) {
        int r = r0 + lk * 4 + reg;
        if (r < n) {
          float v = z[reg];
          sout[(size_t)r * HID + nt * 16 + lm] = (f16)v;
          ssum[nt] += v;
          ssq[nt] += v * v;
        }
      }
    }
  }
  // stats reduce: lanes l, l+16, l+32, l+48 share the same channel set
  f32x4 sumv = {ssum[0], ssum[1], ssum[2], ssum[3]};
  f32x4 sqv = {ssq[0], ssq[1], ssq[2], ssq[3]};
  sumv = xreduce(sumv);
  sqv = xreduce(sqv);
  if (lk == 0) { red4[0][wid][lm] = sumv; red4[1][wid][lm] = sqv; }
  __syncthreads();
  if (t < 16) {
    f32x4 a = red4[0][0][t] + red4[0][1][t] + red4[0][2][t] + red4[0][3][t];
    f32x4 b = red4[1][0][t] + red4[1][1][t] + red4[1][2][t] + red4[1][3][t];
    int js = (blockIdx.x & 15) * 64;  // per-block sub-slot: distinct L2 lines
    atomicAdd(&sumL[js + 0 * 16 + t], a.x);
    atomicAdd(&sumL[js + 1 * 16 + t], a.y);
    atomicAdd(&sumL[js + 2 * 16 + t], a.z);
    atomicAdd(&sumL[js + 3 * 16 + t], a.w);
    atomicAdd(&sumsqL[js + 0 * 16 + t], b.x);
    atomicAdd(&sumsqL[js + 1 * 16 + t], b.y);
    atomicAdd(&sumsqL[js + 2 * 16 + t], b.z);
    atomicAdd(&sumsqL[js + 3 * 16 + t], b.w);
  }
}

// per-block inline BN-affine from the sums slot (sums 16 sub-slots)
__device__ __forceinline__ void stats_to_lds(
    const float* __restrict__ sumL, const float* __restrict__ sumsqL,
    const float* __restrict__ gamma_l, const float* __restrict__ beta_l,
    float* ms, int t, int n) {
  if (t < 64) {
    float s = 0.f, sq = 0.f;
#pragma unroll
    for (int j = 0; j < 16; j++) {
      s += sumL[j * 64 + t];
      sq += sumsqL[j * 64 + t];
    }
    float mu = s / (float)n;
    float var = sq / (float)n - mu * mu;
    float iv = rsqrtf(var + BN_EPS);
    float k1 = iv * gamma_l[t];
    ms[t] = k1;
    ms[64 + t] = beta_l[t] - mu * k1;
  }
  __syncthreads();
}

// hp = dinv * relu(BN(s)): the pre-scaled gather operand for the next layer
__global__ __launch_bounds__(NTHREADS) void k_bnrelu(
    const f16* __restrict__ s, const float* __restrict__ sumL,
    const float* __restrict__ sumsqL, const float* __restrict__ gamma_l,
    const float* __restrict__ beta_l, const float* __restrict__ dinv,
    f16* __restrict__ hp, int n) {
  __shared__ __align__(16) float ms[128];
  int t = threadIdx.x;
  stats_to_lds(sumL, sumsqL, gamma_l, beta_l, ms, t, n);
  int idx = blockIdx.x * NTHREADS + t;  // x4 index
  if (idx < n * (HID / 4)) {
    int c4 = idx & 15;
    int row = idx >> 4;
    f32x4 v = ldh4(s + (size_t)idx * 4);
    f32x4 k1 = *(const f32x4*)(ms + c4 * 4);
    f32x4 k2 = *(const f32x4*)(ms + 64 + c4 * 4);
    v = bnrelu(v, k1, k2);
    float di = dinv[row];
    v = di * v;
    ((f16x4*)hp)[idx] = __builtin_convertvector(v, f16x4);
  }
}

// out = relu(BN_7(s)) @ W_out + b_out   (affine computed inline from slot 7)
__global__ __launch_bounds__(NTHREADS) void k_out(
    const f16* __restrict__ s, const float* __restrict__ sumL,
    const float* __restrict__ sumsqL, const float* __restrict__ gamma_l,
    const float* __restrict__ beta_l, const float* __restrict__ Wout,
    const float* __restrict__ bout, float* __restrict__ out, int n) {
  __shared__ float Ws[HID * OUT_C];
  __shared__ float bs[OUT_C];
  __shared__ __align__(16) float ms[128];
  int t = threadIdx.x;
  for (int m = t; m < HID * OUT_C; m += NTHREADS) Ws[m] = Wout[m];
  if (t < OUT_C) bs[t] = bout[t];
  stats_to_lds(sumL, sumsqL, gamma_l, beta_l, ms, t, n);
  int idx = blockIdx.x * NTHREADS + t;
  if (idx < n * OUT_C) {
    int row = idx / OUT_C;
    int c = idx - row * OUT_C;
    float acc = bs[c];
    const f16* sr = s + (size_t)row * HID;
    for (int kk = 0; kk < HID / 4; kk++) {
      f32x4 a = ldh4(sr + kk * 4);
      f32x4 k1 = *(const f32x4*)(ms + kk * 4);
      f32x4 k2 = *(const f32x4*)(ms + 64 + kk * 4);
      a = bnrelu(a, k1, k2);
      int k = kk * 4;
      acc += a.x * Ws[(k + 0) * OUT_C + c] + a.y * Ws[(k + 1) * OUT_C + c] +
             a.z * Ws[(k + 2) * OUT_C + c] + a.w * Ws[(k + 3) * OUT_C + c];
    }
    out[idx] = acc;
  }
}

// ---------------- host ----------------

extern "C" void kernel_launch(void* const* d_in, const int* in_sizes, int n_in,
                              void* d_out, int out_size, void* d_ws, size_t ws_size,
                              hipStream_t stream) {
  const float* x = (const float*)d_in[0];
  const int* ei = (const int*)d_in[1];
  const float* W0 = (const float*)d_in[2];
  const float* b0 = (const float*)d_in[3];
  const float* convW = (const float*)d_in[4];
  const float* bn_gamma = (const float*)d_in[5];
  const float* bn_beta = (const float*)d_in[6];
  const float* W_out = (const float*)d_in[7];
  const float* b_out = (const float*)d_in[8];
  float* out = (float*)d_out;

  int n = in_sizes[0] / IN_C;   // 100000
  int E = in_sizes[1] / 2;      // 1600000
  const int* row = ei;
  const int* col = ei + E;
  int NB = (n + (1 << BKT_SHIFT) - 1) >> BKT_SHIFT;  // 196 buckets

  char* w = (char*)d_ws;
  auto alloc = [&](size_t bytes) {
    char* p = w;
    w += (bytes + 255) & ~(size_t)255;
    return p;
  };
  float* dinv    = (float*)alloc((size_t)n * 4);
  int*   offs    = (int*)alloc((size_t)(n + 1) * 4);
  int*   bcnt    = (int*)alloc(512 * 4);
  int*   bbase   = (int*)alloc(512 * 4);
  int*   bcur    = (int*)alloc(512 * 4);
  int*   ew      = (int*)alloc((size_t)E * 4);          // 4B records
  long long* tmp = (long long*)alloc((size_t)E * 8);    // bucketed (col,row)
  f16*   h016    = (f16*)alloc((size_t)n * HID * 2);
  f16*   hp      = (f16*)alloc((size_t)n * HID * 2);    // dinv * relu(BN(s))
  f16*   sv      = (f16*)alloc((size_t)(n + 16) * HID * 2);  // +16 pad rows
  f16*   sb      = (f16*)alloc((size_t)n * HID * 2);    // conv output s_l
  float* sumP    = (float*)alloc((size_t)N_LAYERS * 1024 * 4);
  float* sumsqP  = (float*)alloc((size_t)N_LAYERS * 1024 * 4);

  int gE4 = (E + 4095) / 4096;              // 391 (bhist / bucketA blocks)
  int gRow = (n + 15) / 16;                 // 6250
  int gConv = (gRow + 3) / 4;               // 1563
  int gV = (n * (HID / 4) + NTHREADS - 1) / NTHREADS;

  k_zero<<<33, NTHREADS, 0, stream>>>(sumP, sumsqP, sv + (size_t)n * HID, bcnt);
  k_bhist<<<gE4, NTHREADS, 0, stream>>>(col, bcnt, E, NB);
  k_bscan<<<1, 256, 0, stream>>>(bcnt, bbase, bcur, offs, NB, n, E);
  k_bucketA<<<gE4, NTHREADS, 0, stream>>>(row, col, bcur, tmp, E, NB);
  k_bucketB<<<NB, 512, 0, stream>>>(tmp, bbase, offs, dinv, ew, n);

  k_gemm0<<<512, NTHREADS, 0, stream>>>(x, W0, b0, dinv, h016, hp, n);

  for (int l = 0; l < N_LAYERS; l++) {
    float beta = logf(0.5f / (float)(l + 1) + 1.0f);
    if (l > 0) {  // hp = dinv * relu(BN_{l-1}(s_{l-1})) using slot l-1
      k_bnrelu<<<gV, NTHREADS, 0, stream>>>(
          sb, sumP + (size_t)(l - 1) * 1024, sumsqP + (size_t)(l - 1) * 1024,
          bn_gamma + (l - 1) * HID, bn_beta + (l - 1) * HID, dinv, hp, n);
    }
    k_gather<<<gRow, NTHREADS, 0, stream>>>(hp, h016, dinv, offs, ew, sv, n);
    k_conv<<<gConv, NTHREADS, 0, stream>>>(sv, convW + (size_t)l * HID * HID,
                                           sb, sumP + (size_t)l * 1024,
                                           sumsqP + (size_t)l * 1024, beta, n);
  }

  // s_7 in sb; k_out applies BN_7 (slot 7) + relu inline, then output GEMM
  k_out<<<((size_t)n * OUT_C + NTHREADS - 1) / NTHREADS, NTHREADS, 0, stream>>>(
      sb, sumP + (size_t)7 * 1024, sumsqP + (size_t)7 * 1024,
      bn_gamma + 7 * HID, bn_beta + 7 * HID, W_out, b_out, out, n);
}

// Round 17
// 655.415 us; speedup vs baseline: 2.1229x; 1.0576x over previous
//
#include <hip/hip_runtime.h>
#include <math.h>

#define NTHREADS 256
#define IN_C 128
#define HID 64
#define OUT_C 40
#define N_LAYERS 8
#define ALPHA 0.1f
#define BN_EPS 1e-5f
#define BKT_SHIFT 9   // 512-node buckets for the CSR build

typedef float f32x4 __attribute__((ext_vector_type(4)));
typedef _Float16 f16;
typedef _Float16 f16x4 __attribute__((ext_vector_type(4)));
typedef _Float16 f16x8 __attribute__((ext_vector_type(8)));

__device__ __forceinline__ f32x4 ld4(const float* p) { return *(const f32x4*)p; }

__device__ __forceinline__ f32x4 ldh4(const f16* p) {
  f16x4 v = *(const f16x4*)p;
  return __builtin_convertvector(v, f32x4);
}

__device__ __forceinline__ f32x4 bnrelu(f32x4 v, f32x4 k1, f32x4 k2) {
  f32x4 r = v * k1 + k2;
  r.x = fmaxf(r.x, 0.f); r.y = fmaxf(r.y, 0.f);
  r.z = fmaxf(r.z, 0.f); r.w = fmaxf(r.w, 0.f);
  return r;
}

// sum over the 4 16-lane groups (lanes l, l+16, l+32, l+48)
__device__ __forceinline__ f32x4 xreduce(f32x4 v) {
  v.x += __shfl_xor(v.x, 16); v.y += __shfl_xor(v.y, 16);
  v.z += __shfl_xor(v.z, 16); v.w += __shfl_xor(v.w, 16);
  v.x += __shfl_xor(v.x, 32); v.y += __shfl_xor(v.y, 32);
  v.z += __shfl_xor(v.z, 32); v.w += __shfl_xor(v.w, 32);
  return v;
}

// ---------------- setup kernels ----------------

// sums layout: per-layer slot l at [l*1024]; sub-slot j (= blockIdx & 15)
// for channel c at [j*64 + c] (r14: spreads BN-stat atomic contention).
__global__ void k_zero(float* __restrict__ sumP, float* __restrict__ sumsqP,
                       f16* __restrict__ svpad, int* __restrict__ bcnt) {
  int i = blockIdx.x * NTHREADS + threadIdx.x;
  if (i < N_LAYERS * 1024) { sumP[i] = 0.f; sumsqP[i] = 0.f; }
  if (i < 256) {  // zero the 16 pad rows of sv (MFMA A-frag tail)
    f16x4 z = {(f16)0.f, (f16)0.f, (f16)0.f, (f16)0.f};
    ((f16x4*)svpad)[i] = z;
  }
  if (blockIdx.x == 0 && threadIdx.x < 256) bcnt[threadIdx.x] = 0;
}

// 196-bucket histogram of col: LDS-aggregated, one global atomic per
// (block,bucket) — no per-node atomics.
__global__ __launch_bounds__(NTHREADS) void k_bhist(
    const int* __restrict__ col, int* __restrict__ bcnt, int E, int nb) {
  __shared__ int lhist[512];
  int t = threadIdx.x;
  for (int i = t; i < nb; i += NTHREADS) lhist[i] = 0;
  __syncthreads();
  int start = blockIdx.x * 4096;
  int end = min(E, start + 4096);
  for (int e = start + t; e < end; e += NTHREADS)
    atomicAdd(&lhist[col[e] >> BKT_SHIFT], 1);
  __syncthreads();
  for (int i = t; i < nb; i += NTHREADS) {
    int c = lhist[i];
    if (c) atomicAdd(&bcnt[i], c);
  }
}

// 1-block scan of bucket totals -> bbase (exclusive), bcur seed, offs[n]=E
__global__ void k_bscan(const int* __restrict__ bcnt, int* __restrict__ bbase,
                        int* __restrict__ bcur, int* __restrict__ offs,
                        int nb, int n, int E) {
  __shared__ int sh[256];
  int t = threadIdx.x;  // 256 threads, nb <= 256
  int v = (t < nb) ? bcnt[t] : 0;
  sh[t] = v;
  __syncthreads();
  int run = v;
  for (int d = 1; d < 256; d <<= 1) {
    int add = (t >= d) ? sh[t - d] : 0;
    __syncthreads();
    run += add;
    sh[t] = run;
    __syncthreads();
  }
  if (t < nb) {
    bbase[t] = run - v;
    bcur[t] = run - v;
  }
  if (t == 0) {
    bbase[nb] = E;
    offs[n] = E;
  }
}

// pass A: scatter (col,row) into contiguous bucket regions (L2-local).
__global__ __launch_bounds__(NTHREADS) void k_bucketA(
    const int* __restrict__ row, const int* __restrict__ col,
    int* __restrict__ bcur, long long* __restrict__ tmp, int E, int nb) {
  __shared__ int lhist[512];
  __shared__ int lbase[512];
  int t = threadIdx.x;
  for (int i = t; i < nb; i += NTHREADS) lhist[i] = 0;
  __syncthreads();
  int start = blockIdx.x * 4096;
  int end = min(E, start + 4096);
  for (int e = start + t; e < end; e += NTHREADS)
    atomicAdd(&lhist[col[e] >> BKT_SHIFT], 1);
  __syncthreads();
  for (int i = t; i < nb; i += NTHREADS) {
    int c = lhist[i];
    lbase[i] = c ? atomicAdd(&bcur[i], c) : 0;
    lhist[i] = 0;
  }
  __syncthreads();
  for (int e = start + t; e < end; e += NTHREADS) {
    int cl = col[e];
    int b = cl >> BKT_SHIFT;
    int slot = atomicAdd(&lhist[b], 1);
    tmp[lbase[b] + slot] = ((long long)cl << 32) | (unsigned int)row[e];
  }
}

// pass B (512 threads): per bucket — LDS per-node counts, LDS scan, write
// offs/dinv densely, then place records via LDS cursors. ZERO global atomics.
__global__ __launch_bounds__(512) void k_bucketB(
    const long long* __restrict__ tmp, const int* __restrict__ bbase,
    int* __restrict__ offs, float* __restrict__ dinv,
    int* __restrict__ ew, int n) {
  __shared__ int lcnt[512];
  __shared__ int lcur[512];
  int b = blockIdx.x;
  int t = threadIdx.x;
  int lo = b << BKT_SHIFT;
  int s = bbase[b], e2 = bbase[b + 1];
  lcnt[t] = 0;
  __syncthreads();
  for (int j = s + t; j < e2; j += 512)
    atomicAdd(&lcnt[(int)(tmp[j] >> 32) - lo], 1);
  __syncthreads();
  int v = lcnt[t];
  int run = v;
  for (int d = 1; d < 512; d <<= 1) {
    int add = (t >= d) ? lcnt[t - d] : 0;
    __syncthreads();
    run += add;
    lcnt[t] = run;
    __syncthreads();
  }
  int node = lo + t;
  int myoff = s + run - v;  // exclusive position of this node's edge list
  if (node < n) {
    offs[node] = myoff;
    dinv[node] = rsqrtf((float)v + 1.0f);
  }
  lcur[t] = myoff;
  __syncthreads();
  for (int j = s + t; j < e2; j += 512) {
    long long r = tmp[j];
    int cl = (int)(r >> 32);
    int pos = atomicAdd(&lcur[cl - lo], 1);  // LDS atomic
    ew[pos] = (int)(r & 0xffffffffLL);
  }
}

// ---------------- MFMA gemm0: h0 = relu(x@W0+b0), hp = dinv*h0 ----------------
__global__ void k_gemm0(
    const float* __restrict__ x, const float* __restrict__ W0,
    const float* __restrict__ b0, const float* __restrict__ dinv,
    f16* __restrict__ h016, f16* __restrict__ hp, int n) {
  int t = threadIdx.x;
  int lane = t & 63, wid = t >> 6;
  int lm = lane & 15, lk = lane >> 4;
  f16x8 bf[4][4];
  float bv[4];
#pragma unroll
  for (int nt = 0; nt < 4; nt++) {
    int c = nt * 16 + lm;
    bv[nt] = b0[c];
#pragma unroll
    for (int ks = 0; ks < 4; ks++) {
#pragma unroll
      for (int i = 0; i < 8; i++) {
        bf[nt][ks][i] = (f16)W0[(ks * 32 + lk * 8 + i) * HID + c];
      }
    }
  }
  int nblk = (n + 15) >> 4;
  for (int blk = blockIdx.x * 4 + wid; blk < nblk; blk += gridDim.x * 4) {
    int r0 = blk * 16;
    int rA = min(r0 + lm, n - 1);
    const float* xr = x + (size_t)rA * IN_C + lk * 8;
    f16x8 af[4];
#pragma unroll
    for (int ks = 0; ks < 4; ks++) {
      f32x4 lo = ld4(xr + ks * 32);
      f32x4 hi = ld4(xr + ks * 32 + 4);
      f16x4 l16 = __builtin_convertvector(lo, f16x4);
      f16x4 h16 = __builtin_convertvector(hi, f16x4);
#pragma unroll
      for (int i = 0; i < 4; i++) { af[ks][i] = l16[i]; af[ks][4 + i] = h16[i]; }
    }
    float dv[4];
#pragma unroll
    for (int reg = 0; reg < 4; reg++)
      dv[reg] = dinv[min(r0 + lk * 4 + reg, n - 1)];
#pragma unroll
    for (int nt = 0; nt < 4; nt++) {
      f32x4 z = {0.f, 0.f, 0.f, 0.f};
      z = __builtin_amdgcn_mfma_f32_16x16x32_f16(af[0], bf[nt][0], z, 0, 0, 0);
      z = __builtin_amdgcn_mfma_f32_16x16x32_f16(af[1], bf[nt][1], z, 0, 0, 0);
      z = __builtin_amdgcn_mfma_f32_16x16x32_f16(af[2], bf[nt][2], z, 0, 0, 0);
      z = __builtin_amdgcn_mfma_f32_16x16x32_f16(af[3], bf[nt][3], z, 0, 0, 0);
#pragma unroll
      for (int reg = 0; reg < 4; reg++) {
        int r = r0 + lk * 4 + reg;
        if (r < n) {
          float v = fmaxf(z[reg] + bv[nt], 0.f);
          h016[(size_t)r * HID + nt * 16 + lm] = (f16)v;
          hp[(size_t)r * HID + nt * 16 + lm] = (f16)(dv[reg] * v);
        }
      }
    }
  }
}

// ---------------- gather-only kernel (barrier-free) ----------
// sv[i] = (1-a)*di*(acc + hp[i]) + a*h0[i],   acc = sum_j hp[src_j]
__global__ void k_gather(
    const f16* __restrict__ hp, const f16* __restrict__ h0,
    const float* __restrict__ dinv, const int* __restrict__ offs,
    const int* __restrict__ ew, f16* __restrict__ sv, int n) {
  int t = threadIdx.x;
  int lane = t & 63;
  int eg = lane >> 4, li = lane & 15, c4 = li << 2;
  int i = blockIdx.x * 16 + (t >> 6) * 4 + eg;  // this group's row
  if (i >= n) return;
  int jb = offs[i], je = offs[i + 1];
  float di = dinv[i];
  f16x4 hs16 = *(const f16x4*)(hp + (size_t)i * HID + c4);
  f16x4 h016v = *(const f16x4*)(h0 + (size_t)i * HID + c4);
  f32x4 acc = {0.f, 0.f, 0.f, 0.f};
  int j = jb;
  for (; j + 8 <= je; j += 8) {
    int q0 = ew[j + 0];
    int q1 = ew[j + 1];
    int q2 = ew[j + 2];
    int q3 = ew[j + 3];
    int q4 = ew[j + 4];
    int q5 = ew[j + 5];
    int q6 = ew[j + 6];
    int q7 = ew[j + 7];
    f16x4 u0 = *(const f16x4*)(hp + (size_t)q0 * HID + c4);
    f16x4 u1 = *(const f16x4*)(hp + (size_t)q1 * HID + c4);
    f16x4 u2 = *(const f16x4*)(hp + (size_t)q2 * HID + c4);
    f16x4 u3 = *(const f16x4*)(hp + (size_t)q3 * HID + c4);
    f16x4 u4 = *(const f16x4*)(hp + (size_t)q4 * HID + c4);
    f16x4 u5 = *(const f16x4*)(hp + (size_t)q5 * HID + c4);
    f16x4 u6 = *(const f16x4*)(hp + (size_t)q6 * HID + c4);
    f16x4 u7 = *(const f16x4*)(hp + (size_t)q7 * HID + c4);
    acc += __builtin_convertvector(u0, f32x4);
    acc += __builtin_convertvector(u1, f32x4);
    acc += __builtin_convertvector(u2, f32x4);
    acc += __builtin_convertvector(u3, f32x4);
    acc += __builtin_convertvector(u4, f32x4);
    acc += __builtin_convertvector(u5, f32x4);
    acc += __builtin_convertvector(u6, f32x4);
    acc += __builtin_convertvector(u7, f32x4);
  }
  for (; j < je; j++) {
    acc += ldh4(hp + (size_t)ew[j] * HID + c4);
  }
  f32x4 hs = __builtin_convertvector(hs16, f32x4);
  f32x4 h0v = __builtin_convertvector(h016v, f32x4);
  f32x4 sval = (1.f - ALPHA) * (di * (acc + hs)) + ALPHA * h0v;
  *(f16x4*)(sv + (size_t)i * HID + c4) = __builtin_convertvector(sval, f16x4);
}

// ---------------- MFMA conv + BN stats (atomics spread over 16 sub-slots) ---
// S2 = SV @ W',  W' = (1-beta)I + beta*W (built during LDS staging, fp16).
__global__ __launch_bounds__(NTHREADS) void k_conv(
    const f16* __restrict__ sv, const float* __restrict__ Wl,
    f16* __restrict__ sout, float* __restrict__ sumL,
    float* __restrict__ sumsqL, float beta, int n) {
  __shared__ __align__(16) float Wsh[HID * HID];  // W' staged, 16 KB
  __shared__ f32x4 red4[2][4][16];
  int t = threadIdx.x;
  // stage W' = beta*W + (1-beta)*I
  for (int m = t; m < HID * HID / 4; m += NTHREADS) {
    f32x4 wv = ((const f32x4*)Wl)[m];
    wv *= beta;
    int base = m * 4;
    int k = base >> 6, c0 = base & 63;
    if (k >= c0 && k < c0 + 4) wv[k - c0] += (1.f - beta);
    ((f32x4*)Wsh)[m] = wv;
  }
  __syncthreads();
  int lane = t & 63, wid = t >> 6;
  int lm = lane & 15, lk = lane >> 4;
  // B fragments: 4 col-tiles x 2 K-steps, cast to fp16
  f16x8 bf[4][2];
#pragma unroll
  for (int nt = 0; nt < 4; nt++) {
#pragma unroll
    for (int ks = 0; ks < 2; ks++) {
      int c = nt * 16 + lm;
#pragma unroll
      for (int i = 0; i < 8; i++) {
        int k = ks * 32 + lk * 8 + i;
        bf[nt][ks][i] = (f16)Wsh[k * HID + c];
      }
    }
  }
  float ssum[4] = {0.f, 0.f, 0.f, 0.f}, ssq[4] = {0.f, 0.f, 0.f, 0.f};
  int nblk = (n + 15) >> 4;
  for (int blk = blockIdx.x * 4 + wid; blk < nblk; blk += gridDim.x * 4) {
    int r0 = blk * 16;
    const f16* ap = sv + (size_t)(r0 + lm) * HID + lk * 8;  // pad rows zeroed
    f16x8 a0 = *(const f16x8*)(ap);
    f16x8 a1 = *(const f16x8*)(ap + 32);
#pragma unroll
    for (int nt = 0; nt < 4; nt++) {
      f32x4 z = {0.f, 0.f, 0.f, 0.f};
      z = __builtin_amdgcn_mfma_f32_16x16x32_f16(a0, bf[nt][0], z, 0, 0, 0);
      z = __builtin_amdgcn_mfma_f32_16x16x32_f16(a1, bf[nt][1], z, 0, 0, 0);
#pragma unroll
      for (int reg = 0; reg < 4; reg++) {
        int r = r0 + lk * 4 + reg;
        if (r < n) {
          float v = z[reg];
          sout[(size_t)r * HID + nt * 16 + lm] = (f16)v;
          ssum[nt] += v;
          ssq[nt] += v * v;
        }
      }
    }
  }
  // stats reduce: lanes l, l+16, l+32, l+48 share the same channel set
  f32x4 sumv = {ssum[0], ssum[1], ssum[2], ssum[3]};
  f32x4 sqv = {ssq[0], ssq[1], ssq[2], ssq[3]};
  sumv = xreduce(sumv);
  sqv = xreduce(sqv);
  if (lk == 0) { red4[0][wid][lm] = sumv; red4[1][wid][lm] = sqv; }
  __syncthreads();
  if (t < 16) {
    f32x4 a = red4[0][0][t] + red4[0][1][t] + red4[0][2][t] + red4[0][3][t];
    f32x4 b = red4[1][0][t] + red4[1][1][t] + red4[1][2][t] + red4[1][3][t];
    int js = (blockIdx.x & 15) * 64;  // per-block sub-slot: distinct L2 lines
    atomicAdd(&sumL[js + 0 * 16 + t], a.x);
    atomicAdd(&sumL[js + 1 * 16 + t], a.y);
    atomicAdd(&sumL[js + 2 * 16 + t], a.z);
    atomicAdd(&sumL[js + 3 * 16 + t], a.w);
    atomicAdd(&sumsqL[js + 0 * 16 + t], b.x);
    atomicAdd(&sumsqL[js + 1 * 16 + t], b.y);
    atomicAdd(&sumsqL[js + 2 * 16 + t], b.z);
    atomicAdd(&sumsqL[js + 3 * 16 + t], b.w);
  }
}

// per-block inline BN-affine from the sums slot (sums 16 sub-slots)
__device__ __forceinline__ void stats_to_lds(
    const float* __restrict__ sumL, const float* __restrict__ sumsqL,
    const float* __restrict__ gamma_l, const float* __restrict__ beta_l,
    float* ms, int t, int n) {
  if (t < 64) {
    float s = 0.f, sq = 0.f;
#pragma unroll
    for (int j = 0; j < 16; j++) {
      s += sumL[j * 64 + t];
      sq += sumsqL[j * 64 + t];
    }
    float mu = s / (float)n;
    float var = sq / (float)n - mu * mu;
    float iv = rsqrtf(var + BN_EPS);
    float k1 = iv * gamma_l[t];
    ms[t] = k1;
    ms[64 + t] = beta_l[t] - mu * k1;
  }
  __syncthreads();
}

// hp = dinv * relu(BN(s)): the pre-scaled gather operand for the next layer
__global__ __launch_bounds__(NTHREADS) void k_bnrelu(
    const f16* __restrict__ s, const float* __restrict__ sumL,
    const float* __restrict__ sumsqL, const float* __restrict__ gamma_l,
    const float* __restrict__ beta_l, const float* __restrict__ dinv,
    f16* __restrict__ hp, int n) {
  __shared__ __align__(16) float ms[128];
  int t = threadIdx.x;
  stats_to_lds(sumL, sumsqL, gamma_l, beta_l, ms, t, n);
  int idx = blockIdx.x * NTHREADS + t;  // x4 index
  if (idx < n * (HID / 4)) {
    int c4 = idx & 15;
    int row = idx >> 4;
    f32x4 v = ldh4(s + (size_t)idx * 4);
    f32x4 k1 = *(const f32x4*)(ms + c4 * 4);
    f32x4 k2 = *(const f32x4*)(ms + 64 + c4 * 4);
    v = bnrelu(v, k1, k2);
    float di = dinv[row];
    v = di * v;
    ((f16x4*)hp)[idx] = __builtin_convertvector(v, f16x4);
  }
}

// ---------------- MFMA k_out: out = relu(BN_7(s)) @ W_out + b_out ----------
// Per wave: one 16-row tile; 3 col-tiles (48 >= 40, tail cols zero);
// BN+ReLU applied in-register to A-rows via per-lane hoisted k1/k2;
// 6 MFMAs/tile. No W staging in LDS (r16: 4.87M bank conflicts from the
// scalar 40-stride Ws reads were 60 us).
__global__ __launch_bounds__(NTHREADS) void k_out(
    const f16* __restrict__ s, const float* __restrict__ sumL,
    const float* __restrict__ sumsqL, const float* __restrict__ gamma_l,
    const float* __restrict__ beta_l, const float* __restrict__ Wout,
    const float* __restrict__ bout, float* __restrict__ out, int n) {
  __shared__ __align__(16) float ms[128];
  int t = threadIdx.x;
  stats_to_lds(sumL, sumsqL, gamma_l, beta_l, ms, t, n);
  int lane = t & 63, wid = t >> 6;
  int lm = lane & 15, lk = lane >> 4;
  // B-frags: col c = nt*16+lm (zero for c>=40); k = ks*32 + lk*8 + i
  f16x8 bf[3][2];
  float bv[3];
#pragma unroll
  for (int nt = 0; nt < 3; nt++) {
    int c = nt * 16 + lm;
    bv[nt] = (c < OUT_C) ? bout[c] : 0.f;
#pragma unroll
    for (int ks = 0; ks < 2; ks++) {
#pragma unroll
      for (int i = 0; i < 8; i++) {
        int k = ks * 32 + lk * 8 + i;
        bf[nt][ks][i] = (c < OUT_C) ? (f16)Wout[k * OUT_C + c] : (f16)0.f;
      }
    }
  }
  // per-lane BN affine for the A-row channels this lane loads:
  // a0 covers k = lk*8..lk*8+7, a1 covers k = 32+lk*8..32+lk*8+7
  float k1a[8], k2a[8], k1b[8], k2b[8];
#pragma unroll
  for (int i = 0; i < 8; i++) {
    k1a[i] = ms[lk * 8 + i];
    k2a[i] = ms[64 + lk * 8 + i];
    k1b[i] = ms[32 + lk * 8 + i];
    k2b[i] = ms[64 + 32 + lk * 8 + i];
  }
  int nblk = (n + 15) >> 4;
  for (int blk = blockIdx.x * 4 + wid; blk < nblk; blk += gridDim.x * 4) {
    int r0 = blk * 16;
    int rA = min(r0 + lm, n - 1);
    const f16* sr = s + (size_t)rA * HID + lk * 8;
    f16x8 s0 = *(const f16x8*)(sr);
    f16x8 s1 = *(const f16x8*)(sr + 32);
    f16x8 a0, a1;
#pragma unroll
    for (int i = 0; i < 8; i++) {
      a0[i] = (f16)fmaxf((float)s0[i] * k1a[i] + k2a[i], 0.f);
      a1[i] = (f16)fmaxf((float)s1[i] * k1b[i] + k2b[i], 0.f);
    }
#pragma unroll
    for (int nt = 0; nt < 3; nt++) {
      int c = nt * 16 + lm;
      f32x4 z = {0.f, 0.f, 0.f, 0.f};
      z = __builtin_amdgcn_mfma_f32_16x16x32_f16(a0, bf[nt][0], z, 0, 0, 0);
      z = __builtin_amdgcn_mfma_f32_16x16x32_f16(a1, bf[nt][1], z, 0, 0, 0);
#pragma unroll
      for (int reg = 0; reg < 4; reg++) {
        int r = r0 + lk * 4 + reg;
        if (r < n && c < OUT_C) {
          out[(size_t)r * OUT_C + c] = z[reg] + bv[nt];
        }
      }
    }
  }
}

// ---------------- host ----------------

extern "C" void kernel_launch(void* const* d_in, const int* in_sizes, int n_in,
                              void* d_out, int out_size, void* d_ws, size_t ws_size,
                              hipStream_t stream) {
  const float* x = (const float*)d_in[0];
  const int* ei = (const int*)d_in[1];
  const float* W0 = (const float*)d_in[2];
  const float* b0 = (const float*)d_in[3];
  const float* convW = (const float*)d_in[4];
  const float* bn_gamma = (const float*)d_in[5];
  const float* bn_beta = (const float*)d_in[6];
  const float* W_out = (const float*)d_in[7];
  const float* b_out = (const float*)d_in[8];
  float* out = (float*)d_out;

  int n = in_sizes[0] / IN_C;   // 100000
  int E = in_sizes[1] / 2;      // 1600000
  const int* row = ei;
  const int* col = ei + E;
  int NB = (n + (1 << BKT_SHIFT) - 1) >> BKT_SHIFT;  // 196 buckets

  char* w = (char*)d_ws;
  auto alloc = [&](size_t bytes) {
    char* p = w;
    w += (bytes + 255) & ~(size_t)255;
    return p;
  };
  float* dinv    = (float*)alloc((size_t)n * 4);
  int*   offs    = (int*)alloc((size_t)(n + 1) * 4);
  int*   bcnt    = (int*)alloc(512 * 4);
  int*   bbase   = (int*)alloc(512 * 4);
  int*   bcur    = (int*)alloc(512 * 4);
  int*   ew      = (int*)alloc((size_t)E * 4);          // 4B records
  long long* tmp = (long long*)alloc((size_t)E * 8);    // bucketed (col,row)
  f16*   h016    = (f16*)alloc((size_t)n * HID * 2);
  f16*   hp      = (f16*)alloc((size_t)n * HID * 2);    // dinv * relu(BN(s))
  f16*   sv      = (f16*)alloc((size_t)(n + 16) * HID * 2);  // +16 pad rows
  f16*   sb      = (f16*)alloc((size_t)n * HID * 2);    // conv output s_l
  float* sumP    = (float*)alloc((size_t)N_LAYERS * 1024 * 4);
  float* sumsqP  = (float*)alloc((size_t)N_LAYERS * 1024 * 4);

  int gE4 = (E + 4095) / 4096;              // 391 (bhist / bucketA blocks)
  int gRow = (n + 15) / 16;                 // 6250
  int gConv = (gRow + 3) / 4;               // 1563
  int gV = (n * (HID / 4) + NTHREADS - 1) / NTHREADS;

  k_zero<<<33, NTHREADS, 0, stream>>>(sumP, sumsqP, sv + (size_t)n * HID, bcnt);
  k_bhist<<<gE4, NTHREADS, 0, stream>>>(col, bcnt, E, NB);
  k_bscan<<<1, 256, 0, stream>>>(bcnt, bbase, bcur, offs, NB, n, E);
  k_bucketA<<<gE4, NTHREADS, 0, stream>>>(row, col, bcur, tmp, E, NB);
  k_bucketB<<<NB, 512, 0, stream>>>(tmp, bbase, offs, dinv, ew, n);

  k_gemm0<<<512, NTHREADS, 0, stream>>>(x, W0, b0, dinv, h016, hp, n);

  for (int l = 0; l < N_LAYERS; l++) {
    float beta = logf(0.5f / (float)(l + 1) + 1.0f);
    if (l > 0) {  // hp = dinv * relu(BN_{l-1}(s_{l-1})) using slot l-1
      k_bnrelu<<<gV, NTHREADS, 0, stream>>>(
          sb, sumP + (size_t)(l - 1) * 1024, sumsqP + (size_t)(l - 1) * 1024,
          bn_gamma + (l - 1) * HID, bn_beta + (l - 1) * HID, dinv, hp, n);
    }
    k_gather<<<gRow, NTHREADS, 0, stream>>>(hp, h016, dinv, offs, ew, sv, n);
    k_conv<<<gConv, NTHREADS, 0, stream>>>(sv, convW + (size_t)l * HID * HID,
                                           sb, sumP + (size_t)l * 1024,
                                           sumsqP + (size_t)l * 1024, beta, n);
  }

  // s_7 in sb; k_out applies BN_7 (slot 7) + relu via MFMA, then output GEMM
  k_out<<<gConv, NTHREADS, 0, stream>>>(
      sb, sumP + (size_t)7 * 1024, sumsqP + (size_t)7 * 1024,
      bn_gamma + 7 * HID, bn_beta + 7 * HID, W_out, b_out, out, n);
}